// Round 7
// baseline (623.815 us; speedup 1.0000x reference)
//
#include <hip/hip_runtime.h>
#include <hip/hip_bf16.h>
#include <math.h>

// ---------------------------------------------------------------------------
// LIF layer, round 17: bf16x3 MFMA GEMM, A-DIRECT-TO-REGISTER (no LDS for A)
// + B-only 3-slot LDS ring + counted vmcnt + banded scan + b-grouped repair.
//
// R16 post-mortem: neutral. Accounting showed the gemm is LDS-BW bound:
// 176 KB LDS traffic/step (128 read + 48 write) @ ~112 B/cyc/CU = 1607 cy
// == measured 1570 cy/step. Scheduling can't fix volume.
// R17: A frags load straight from global into registers (per-lane 16 B at
// the blocked-layout address; dup 2x absorbed by L1/L2), double-buffered a
// full MFMA cluster ahead. B stays in a 3-slot LDS ring (16 KB write +
// 64 KB read per step) -> LDS ~730 cy < MFMA 646+. vmcnt(2) proves, at each
// step top, this step's 8 A-loads and the next slot's B-stage landed
// (queue: [.., s(j+1), A(j), s(j+2)] -> leave newest 2). Tails vmcnt(0).
// MFMA sequence bitwise identical -> absmax 0.0.
// ---------------------------------------------------------------------------

typedef unsigned short u16;
typedef __attribute__((ext_vector_type(8))) short bf16x8;
typedef __attribute__((ext_vector_type(4))) float f32x4;

constexpr int T_STEPS = 64;
constexpr int BATCH   = 128;
constexpr int K_DIM   = 2048;
constexpr int N_DIM   = 2048;
constexpr int M_DIM   = T_STEPS * BATCH;      // 8192
constexpr int NCHAIN  = BATCH * N_DIM;        // 262144

constexpr float DECAY_F32 = (float)0.6065306597126334;
constexpr float BAND      = 5e-4f;

#define GLDS16(g, l) __builtin_amdgcn_global_load_lds(                       \
    (const __attribute__((address_space(1))) void*)(g),                      \
    (__attribute__((address_space(3))) void*)(l), 16, 0, 0)

// ---------------------------------------------------------------------------
// k2: Dekker split f32 -> bf16 hi/lo, 4 elems/thread; block 0 also zeroes
// the 128 per-b worklist counters.
// ---------------------------------------------------------------------------
__global__ __launch_bounds__(256)
void split_bf16(const float* __restrict__ X, const float* __restrict__ W,
                u16* __restrict__ Ah, u16* __restrict__ Al,
                u16* __restrict__ Wh, u16* __restrict__ Wl,
                unsigned int* __restrict__ counters) {
    if (blockIdx.x == 0 && threadIdx.x < 128) counters[threadIdx.x] = 0u;

    constexpr int NA4 = (M_DIM * K_DIM) / 4;
    constexpr int NW4 = (N_DIM * K_DIM) / 4;
    const int i = blockIdx.x * 256 + threadIdx.x;
    const float* src; u16* dh; u16* dl; int base;
    if (i < NA4)            { src = X; dh = Ah; dl = Al; base = i; }
    else if (i < NA4 + NW4) { src = W; dh = Wh; dl = Wl; base = i - NA4; }
    else return;

    const float4 v = *(const float4*)(src + (size_t)base * 4);
    const float f[4] = {v.x, v.y, v.z, v.w};
    unsigned int hp[2], lp[2];
#pragma unroll
    for (int q = 0; q < 4; q += 2) {
        u16 hh[2], ll[2];
#pragma unroll
        for (int e = 0; e < 2; e++) {
            __hip_bfloat16 hb = __float2bfloat16(f[q + e]);
            const float hf = __bfloat162float(hb);
            __hip_bfloat16 lb = __float2bfloat16(f[q + e] - hf);
            hh[e] = *(u16*)&hb;
            ll[e] = *(u16*)&lb;
        }
        hp[q >> 1] = (unsigned int)hh[0] | ((unsigned int)hh[1] << 16);
        lp[q >> 1] = (unsigned int)ll[0] | ((unsigned int)ll[1] << 16);
    }
    *(uint2*)(dh + (size_t)base * 4) = make_uint2(hp[0], hp[1]);
    *(uint2*)(dl + (size_t)base * 4) = make_uint2(lp[0], lp[1]);
}

// ---------------------------------------------------------------------------
// k3: bf16x3 MFMA GEMM (hh + hl + lh), 256x128 tile, 8 waves (4m x 2n),
// BK=32. A: global->register, double-buffered. B: 3-slot LDS ring via
// gload_lds, frags register-double-buffered. Counted vmcnt(2) sync.
// ---------------------------------------------------------------------------
__global__ __launch_bounds__(512, 2)
void gemm_bf16x3r(const u16* __restrict__ Ah, const u16* __restrict__ Al,
                  const u16* __restrict__ Bh, const u16* __restrict__ Bl,
                  const float* __restrict__ bias, float* __restrict__ C) {
    extern __shared__ __align__(16) u16 smem[];
    u16* const sBh = smem;              // [3][4096]
    u16* const sBl = smem + 3 * 4096;   // [3][4096]

    const int tid  = threadIdx.x;
    const int m0   = blockIdx.y * 256;
    const int n0   = blockIdx.x * 128;
    const int lane = tid & 63;
    const int wave = tid >> 6;     // 0..7
    const int wm   = wave >> 1;    // 0..3 (64-row slab)
    const int wn   = wave & 1;     // 0..1 (64-col slab)

    // B staging source (blocked layout, entry = tid) and LDS dest base
    const size_t b0 =
        (size_t)(n0 + (tid >> 6) * 16 + (tid & 15)) * K_DIM + ((tid >> 4) & 3) * 8;
    const int lB0 = wave * 512;    // u16 offset within a slot; HW adds lane*16B

    // per-lane A fragment base pointers (row-blocked MFMA layout)
    const u16* pAh[4];
    const u16* pAl[4];
#pragma unroll
    for (int ti = 0; ti < 4; ti++) {
        const size_t off =
            (size_t)(m0 + wm * 64 + ti * 16 + (lane & 15)) * K_DIM + (lane >> 4) * 8;
        pAh[ti] = Ah + off;
        pAl[ti] = Al + off;
    }

    f32x4 acc[4][4];
#pragma unroll
    for (int i = 0; i < 4; i++)
#pragma unroll
        for (int j = 0; j < 4; j++) acc[i][j] = (f32x4){0.f, 0.f, 0.f, 0.f};

    bf16x8 fahA[4], falA[4], fbhA[4], fblA[4];
    bf16x8 fahB[4], falB[4], fbhB[4], fblB[4];

#define STAGEB(s, kc) do {                                                   \
        const int kn_ = (kc) * 32;                                           \
        GLDS16(Bh + b0 + kn_, sBh + (s) * 4096 + lB0);                       \
        GLDS16(Bl + b0 + kn_, sBl + (s) * 4096 + lB0);                       \
    } while (0)

#define LOADA(SET, kc) do {                                                  \
        const int ko_ = (kc) * 32;                                           \
        _Pragma("unroll")                                                    \
        for (int ti = 0; ti < 4; ti++) {                                     \
            fah##SET[ti] = *(const bf16x8*)(pAh[ti] + ko_);                  \
            fal##SET[ti] = *(const bf16x8*)(pAl[ti] + ko_);                  \
        }                                                                    \
    } while (0)

#define LOADFB(SET, s) do {                                                  \
        const int sB_ = (s) * 4096;                                          \
        _Pragma("unroll")                                                    \
        for (int tj = 0; tj < 4; tj++) {                                     \
            const int tb = wn * 4 + tj;                                      \
            fbh##SET[tj] = *(const bf16x8*)&sBh[sB_ + (tb * 64 + lane) * 8]; \
            fbl##SET[tj] = *(const bf16x8*)&sBl[sB_ + (tb * 64 + lane) * 8]; \
        }                                                                    \
    } while (0)

#define COMPUTE(SET) do {                                                    \
        __builtin_amdgcn_s_setprio(1);                                       \
        _Pragma("unroll")                                                    \
        for (int ti = 0; ti < 4; ti++)                                       \
        _Pragma("unroll")                                                    \
        for (int tj = 0; tj < 4; tj++) {                                     \
            acc[ti][tj] = __builtin_amdgcn_mfma_f32_16x16x32_bf16(           \
                fah##SET[ti], fbh##SET[tj], acc[ti][tj], 0, 0, 0);           \
            acc[ti][tj] = __builtin_amdgcn_mfma_f32_16x16x32_bf16(           \
                fah##SET[ti], fbl##SET[tj], acc[ti][tj], 0, 0, 0);           \
            acc[ti][tj] = __builtin_amdgcn_mfma_f32_16x16x32_bf16(           \
                fal##SET[ti], fbh##SET[tj], acc[ti][tj], 0, 0, 0);           \
        }                                                                    \
        __builtin_amdgcn_s_setprio(0);                                       \
    } while (0)

#define WAITSYNC(vm) do {                                                    \
        asm volatile("s_waitcnt vmcnt(" #vm ") lgkmcnt(0)" ::: "memory");    \
        __builtin_amdgcn_sched_barrier(0);                                   \
        __builtin_amdgcn_s_barrier();                                        \
        __builtin_amdgcn_sched_barrier(0);                                   \
    } while (0)

#define FENCE __builtin_amdgcn_sched_barrier(0)

    // prologue: A(0) first (oldest), then stages 0..2 -> queue A0(8) s0 s1 s2
    LOADA(A, 0);
    STAGEB(0, 0);
    STAGEB(1, 1);
    STAGEB(2, 2);
    WAITSYNC(4);           // A(0) and stage 0 landed (s1,s2 outstanding)
    LOADFB(A, 0);          // B frags for step 0

    int s1 = 1, sW = 0;    // s1 = slot of stage kc+1; sW = kc%3 write slot
    for (int kc = 0; kc < 62; kc += 2) {
        // even step kc: consume set A
        WAITSYNC(2);       // A(kc) + stage(kc+1) landed; stage(kc+2) may fly
        LOADA(B, kc + 1);
        LOADFB(B, s1);
        if (kc + 3 < 64) STAGEB(sW, kc + 3);
        FENCE;
        COMPUTE(A);
        s1 = (s1 == 2) ? 0 : s1 + 1;
        sW = (sW == 2) ? 0 : sW + 1;
        // odd step kc+1: consume set B
        WAITSYNC(2);
        LOADA(A, kc + 2);
        LOADFB(A, s1);
        if (kc + 4 < 64) STAGEB(sW, kc + 4);
        FENCE;
        COMPUTE(B);
        s1 = (s1 == 2) ? 0 : s1 + 1;
        sW = (sW == 2) ? 0 : sW + 1;
    }
    // peeled step 62 (set A): only A(62) & stage(63) remain -> drain
    WAITSYNC(0);
    LOADA(B, 63);
    LOADFB(B, 0);          // slot 63%3 == 0
    FENCE;
    COMPUTE(A);
    // peeled step 63 (set B)
    WAITSYNC(0);
    COMPUTE(B);

#undef FENCE
#undef WAITSYNC
#undef COMPUTE
#undef LOADFB
#undef LOADA
#undef STAGEB

#pragma unroll
    for (int tj = 0; tj < 4; tj++) {
        const int n  = n0 + wn * 64 + tj * 16 + (lane & 15);
        const float bv = bias[n];
#pragma unroll
        for (int ti = 0; ti < 4; ti++) {
            const int mbase = m0 + wm * 64 + ti * 16 + (lane >> 4) * 4;
#pragma unroll
            for (int r = 0; r < 4; r++)
                C[(size_t)(mbase + r) * N_DIM + n] = acc[ti][tj][r] + bv;
        }
    }
}

// ---------------------------------------------------------------------------
// k4: banded scan; flagged chains go to per-b worklists.
// ---------------------------------------------------------------------------
__global__ __launch_bounds__(256)
void lif_scan_band(float* __restrict__ buf, unsigned int* __restrict__ counters,
                   unsigned int* __restrict__ worklist) {
    const int idx = blockIdx.x * 256 + threadIdx.x;   // chain = b*2048 + o
    float mem = 0.0f;
    bool flag = false;
#pragma unroll
    for (int t = 0; t < T_STEPS; t++) {
        const size_t off = (size_t)t * NCHAIN + idx;
        mem = __fadd_rn(__fmul_rn(mem, DECAY_F32), buf[off]);
        const float d = __fsub_rn(mem, 1.0f);
        const bool spk = d > 0.0f;
        if (fabsf(d) < BAND) flag = true;
        buf[off] = spk ? 1.0f : 0.0f;
        if (spk) mem = __fsub_rn(mem, 1.0f);
    }
    if (flag) {
        const int b = idx >> 11, o = idx & 2047;
        const unsigned int p = atomicAdd(&counters[b], 1u);
        worklist[b * 2048 + p] = (unsigned int)o;
    }
}

// ---------------------------------------------------------------------------
// k5: b-grouped exact repair (R16 coalesced X-staging).
// ---------------------------------------------------------------------------
#define RG 16    // chains per group
#define RJ 4     // block-strides per b
#define BKR 64   // k-chunk (320 = 5*64: panel boundaries land on chunk edges)

__global__ __launch_bounds__(256)
void lif_repair2(const float* __restrict__ X, const float* __restrict__ W,
                 const float* __restrict__ bias,
                 const unsigned int* __restrict__ counters,
                 const unsigned int* __restrict__ worklist,
                 float* __restrict__ out) {
    __shared__ float sX[BKR][T_STEPS + 1];      // [k][t] 16.25 KiB
    __shared__ float sW[RG][BKR + 1];           // [o][k]  4.06 KiB
    __shared__ float scur[T_STEPS][RG + 1];
    __shared__ float sspk[T_STEPS][RG + 1];
    __shared__ int   so[RG];

    const int b = blockIdx.x / RJ;
    const int j = blockIdx.x % RJ;
    const unsigned int n_b = counters[b];
    if (n_b == 0) return;
    const int ngroups = (int)(n_b + RG - 1) / RG;

    const int tid = threadIdx.x;
    const int t   = tid & 63;
    const int oi  = tid >> 6;          // 0..3, owns o-slots 4*oi .. 4*oi+3

    for (int g = j; g < ngroups; g += RJ) {
        if (tid < RG) {
            const int slot = g * RG + tid;
            so[tid] = (slot < (int)n_b) ? (int)worklist[b * 2048 + slot] : -1;
        }
        __syncthreads();

        float Csum[4] = {0.f, 0.f, 0.f, 0.f};
        float P[4]    = {0.f, 0.f, 0.f, 0.f};

        for (int c = 0; c < K_DIM / BKR; c++) {
            if (c > 0 && (c % 5) == 0) {       // k = 320*j panel boundary
#pragma unroll
                for (int q = 0; q < 4; q++) {
                    Csum[q] = __fadd_rn(Csum[q], P[q]);
                    P[q] = 0.f;
                }
            }
            const int k0 = c * BKR;
            // stage X chunk: 64 t x 64 k; lanes 4i..4i+3 read row i's 256 B
            {
                const int ts = tid >> 2;            // 0..63 row
                const int kq = (tid & 3) * 16;      // 0..48 col quarter
                const float* src = &X[(size_t)(ts * BATCH + b) * K_DIM + k0 + kq];
#pragma unroll
                for (int q = 0; q < 4; q++) {
                    const float4 v = *(const float4*)(src + q * 4);
                    sX[kq + q * 4 + 0][ts] = v.x;
                    sX[kq + q * 4 + 1][ts] = v.y;
                    sX[kq + q * 4 + 2][ts] = v.z;
                    sX[kq + q * 4 + 3][ts] = v.w;
                }
            }
            // stage W chunk: 16 o x 64 k, 1 float4 per thread
            {
                const int wo  = tid >> 4;          // 0..15
                const int wkq = (tid & 15) * 4;    // 0..60
                const int o   = so[wo];
                float4 v = {0.f, 0.f, 0.f, 0.f};
                if (o >= 0) v = *(const float4*)&W[(size_t)o * K_DIM + k0 + wkq];
                sW[wo][wkq + 0] = v.x; sW[wo][wkq + 1] = v.y;
                sW[wo][wkq + 2] = v.z; sW[wo][wkq + 3] = v.w;
            }
            __syncthreads();
            // exact sequential-k FMA, 4 independent chains (ILP)
#pragma unroll 8
            for (int k = 0; k < BKR; k++) {
                const float xv = sX[k][t];
#pragma unroll
                for (int q = 0; q < 4; q++)
                    P[q] = fmaf(xv, sW[oi * 4 + q][k], P[q]);
            }
            __syncthreads();
        }
#pragma unroll
        for (int q = 0; q < 4; q++) {
            Csum[q] = __fadd_rn(Csum[q], P[q]);    // final 128-elem panel
            const int o = so[oi * 4 + q];
            scur[t][oi * 4 + q] = (o >= 0) ? __fadd_rn(Csum[q], bias[o]) : 0.f;
        }
        __syncthreads();
        if (tid < RG && so[tid] >= 0) {
            float mem = 0.0f;
            for (int tt = 0; tt < T_STEPS; tt++) {
                mem = __fadd_rn(__fmul_rn(mem, DECAY_F32), scur[tt][tid]);
                const float d = __fsub_rn(mem, 1.0f);
                const bool spk = d > 0.0f;
                sspk[tt][tid] = spk ? 1.0f : 0.0f;
                if (spk) mem = __fsub_rn(mem, 1.0f);
            }
        }
        __syncthreads();
#pragma unroll
        for (int q = 0; q < 4; q++) {
            const int o = so[oi * 4 + q];
            if (o >= 0)
                out[(size_t)t * NCHAIN + (size_t)b * N_DIM + o] = sspk[t][oi * 4 + q];
        }
        __syncthreads();
    }
}

// ---------------------------------------------------------------------------
// FALLBACK (R8, known-passing, ws-free).
// ---------------------------------------------------------------------------
__global__ __launch_bounds__(256)
void lif_openblas_q320(const float* __restrict__ X, const float* __restrict__ W,
                       const float* __restrict__ bias, float* __restrict__ out) {
    __shared__ float As[16][T_STEPS + 4];
    __shared__ float Ws[16][64 + 4];
    __shared__ float curbuf[T_STEPS][64 + 1];
    const int tid = threadIdx.x;
    const int o0 = blockIdx.x * 64, b0 = blockIdx.y;
    const int tm = (tid & 15) * 4, tn = (tid >> 4) * 4;
    float Csum[4][4], Pacc[4][4];
#pragma unroll
    for (int i = 0; i < 4; i++)
#pragma unroll
        for (int j = 0; j < 4; j++) { Csum[i][j] = 0.f; Pacc[i][j] = 0.f; }
    for (int c = 0; c < K_DIM / 16; c++) {
        if (c > 0 && (c % 20) == 0) {
#pragma unroll
            for (int i = 0; i < 4; i++)
#pragma unroll
                for (int j = 0; j < 4; j++) {
                    Csum[i][j] = __fadd_rn(Csum[i][j], Pacc[i][j]);
                    Pacc[i][j] = 0.f;
                }
        }
        const int k0 = c * 16;
        {
            const int t = tid >> 2, kq = (tid & 3) * 4;
            const float4 av = *(const float4*)&X[(size_t)(t * BATCH + b0) * K_DIM + k0 + kq];
            As[kq + 0][t] = av.x; As[kq + 1][t] = av.y;
            As[kq + 2][t] = av.z; As[kq + 3][t] = av.w;
            const float4 wv = *(const float4*)&W[(size_t)(o0 + t) * K_DIM + k0 + kq];
            Ws[kq + 0][t] = wv.x; Ws[kq + 1][t] = wv.y;
            Ws[kq + 2][t] = wv.z; Ws[kq + 3][t] = wv.w;
        }
        __syncthreads();
#pragma unroll
        for (int k = 0; k < 16; k++) {
            float a[4], w[4];
#pragma unroll
            for (int i = 0; i < 4; i++) a[i] = As[k][tm + i];
#pragma unroll
            for (int j = 0; j < 4; j++) w[j] = Ws[k][tn + j];
#pragma unroll
            for (int i = 0; i < 4; i++)
#pragma unroll
                for (int j = 0; j < 4; j++) Pacc[i][j] = fmaf(a[i], w[j], Pacc[i][j]);
        }
        __syncthreads();
    }
#pragma unroll
    for (int i = 0; i < 4; i++)
#pragma unroll
        for (int j = 0; j < 4; j++)
            curbuf[tm + i][tn + j] =
                __fadd_rn(__fadd_rn(Csum[i][j], Pacc[i][j]), bias[o0 + tn + j]);
    __syncthreads();
    if (tid < 64) {
        float mem = 0.0f;
#pragma unroll
        for (int t = 0; t < T_STEPS; t++) {
            mem = __fadd_rn(__fmul_rn(mem, DECAY_F32), curbuf[t][tid]);
            const float d = __fsub_rn(mem, 1.0f);
            const bool spk = d > 0.0f;
            out[(size_t)t * NCHAIN + (size_t)b0 * N_DIM + o0 + tid] = spk ? 1.0f : 0.0f;
            if (spk) mem = __fsub_rn(mem, 1.0f);
        }
    }
}

extern "C" void kernel_launch(void* const* d_in, const int* in_sizes, int n_in,
                              void* d_out, int out_size, void* d_ws, size_t ws_size,
                              hipStream_t stream) {
    const float* x = nullptr; const float* W = nullptr; const float* bias = nullptr;
    for (int i = 0; i < n_in; i++) {
        if      (in_sizes[i] == M_DIM * K_DIM) x    = (const float*)d_in[i];
        else if (in_sizes[i] == N_DIM * K_DIM) W    = (const float*)d_in[i];
        else if (in_sizes[i] == N_DIM)         bias = (const float*)d_in[i];
    }
    if (!x)    x    = (const float*)d_in[0];
    if (!W)    W    = (const float*)d_in[1];
    if (!bias) bias = (const float*)d_in[2];
    float* out = (float*)d_out;

    // workspace layout
    const size_t off_cnt = 0;                                     // 128 u32
    const size_t off_wl  = 512;                                   // 128*2048 u32
    const size_t off_Ah  = off_wl + (size_t)128 * 2048 * 4;       // 1049088
    const size_t szA     = (size_t)M_DIM * K_DIM * 2;             // 32 MiB
    const size_t szW     = (size_t)N_DIM * K_DIM * 2;             //  8 MiB
    const size_t off_Al  = off_Ah + szA;
    const size_t off_Wh  = off_Al + szA;
    const size_t off_Wl  = off_Wh + szW;
    const size_t need    = off_Wl + szW;

    if (ws_size < need) {
        dim3 grid(N_DIM / 64, BATCH);
        lif_openblas_q320<<<grid, 256, 0, stream>>>(x, W, bias, out);
        return;
    }

    char* ws = (char*)d_ws;
    unsigned int* counters = (unsigned int*)(ws + off_cnt);
    unsigned int* worklist = (unsigned int*)(ws + off_wl);
    u16* Ah = (u16*)(ws + off_Ah);
    u16* Al = (u16*)(ws + off_Al);
    u16* Wh = (u16*)(ws + off_Wh);
    u16* Wl = (u16*)(ws + off_Wl);

    split_bf16<<<(M_DIM * K_DIM / 4 + N_DIM * K_DIM / 4) / 256, 256, 0, stream>>>(
        x, W, Ah, Al, Wh, Wl, counters);
    dim3 ggrid(N_DIM / 128, M_DIM / 256);   // (16, 32)
    gemm_bf16x3r<<<ggrid, 512, 49152, stream>>>(Ah, Al, Wh, Wl, bias, out);
    lif_scan_band<<<NCHAIN / 256, 256, 0, stream>>>(out, counters, worklist);
    lif_repair2<<<128 * RJ, 256, 0, stream>>>(x, W, bias, counters, worklist, out);
}

// Round 8
// 470.692 us; speedup vs baseline: 1.3253x; 1.3253x over previous
//
#include <hip/hip_runtime.h>
#include <hip/hip_bf16.h>
#include <math.h>

// ---------------------------------------------------------------------------
// LIF layer, round 18: CONSOLIDATION. gemm = R15's proven 3-stage-ring kernel
// (220.7us, MfmaUtil 41%); R17's A-direct experiment reverted (uncoalesced
// frag loads -> 373us). BAND tightened 5e-4 -> 2e-4: at the first
// spike-divergence step fast/exact mems are within the ~6e-5 GEMM error of
// each other AND of threshold, so every wrong chain still flags with 3.3x
// margin; worklist (and repair's X-restaging + compute) shrinks ~2.5x.
// Tail accounting: split ~35us + scan ~25us + repair ~120-150us of the
// 250us non-GEMM tail -> repair is the target this round.
//
// Pipeline: k2 split(+zero) / k3 gemm (3-stage ring, counted vmcnt) /
//           k4 scan / k5 repair. Fallback: R8 fused exact kernel.
// ---------------------------------------------------------------------------

typedef unsigned short u16;
typedef __attribute__((ext_vector_type(8))) short bf16x8;
typedef __attribute__((ext_vector_type(4))) float f32x4;

constexpr int T_STEPS = 64;
constexpr int BATCH   = 128;
constexpr int K_DIM   = 2048;
constexpr int N_DIM   = 2048;
constexpr int M_DIM   = T_STEPS * BATCH;      // 8192
constexpr int NCHAIN  = BATCH * N_DIM;        // 262144

constexpr float DECAY_F32 = (float)0.6065306597126334;
constexpr float BAND      = 2e-4f;            // was 5e-4; error tail ~6e-5

#define GLDS16(g, l) __builtin_amdgcn_global_load_lds(                       \
    (const __attribute__((address_space(1))) void*)(g),                      \
    (__attribute__((address_space(3))) void*)(l), 16, 0, 0)

// ---------------------------------------------------------------------------
// k2: Dekker split f32 -> bf16 hi/lo, 4 elems/thread; block 0 also zeroes
// the 128 per-b worklist counters.
// ---------------------------------------------------------------------------
__global__ __launch_bounds__(256)
void split_bf16(const float* __restrict__ X, const float* __restrict__ W,
                u16* __restrict__ Ah, u16* __restrict__ Al,
                u16* __restrict__ Wh, u16* __restrict__ Wl,
                unsigned int* __restrict__ counters) {
    if (blockIdx.x == 0 && threadIdx.x < 128) counters[threadIdx.x] = 0u;

    constexpr int NA4 = (M_DIM * K_DIM) / 4;
    constexpr int NW4 = (N_DIM * K_DIM) / 4;
    const int i = blockIdx.x * 256 + threadIdx.x;
    const float* src; u16* dh; u16* dl; int base;
    if (i < NA4)            { src = X; dh = Ah; dl = Al; base = i; }
    else if (i < NA4 + NW4) { src = W; dh = Wh; dl = Wl; base = i - NA4; }
    else return;

    const float4 v = *(const float4*)(src + (size_t)base * 4);
    const float f[4] = {v.x, v.y, v.z, v.w};
    unsigned int hp[2], lp[2];
#pragma unroll
    for (int q = 0; q < 4; q += 2) {
        u16 hh[2], ll[2];
#pragma unroll
        for (int e = 0; e < 2; e++) {
            __hip_bfloat16 hb = __float2bfloat16(f[q + e]);
            const float hf = __bfloat162float(hb);
            __hip_bfloat16 lb = __float2bfloat16(f[q + e] - hf);
            hh[e] = *(u16*)&hb;
            ll[e] = *(u16*)&lb;
        }
        hp[q >> 1] = (unsigned int)hh[0] | ((unsigned int)hh[1] << 16);
        lp[q >> 1] = (unsigned int)ll[0] | ((unsigned int)ll[1] << 16);
    }
    *(uint2*)(dh + (size_t)base * 4) = make_uint2(hp[0], hp[1]);
    *(uint2*)(dl + (size_t)base * 4) = make_uint2(lp[0], lp[1]);
}

// ---------------------------------------------------------------------------
// k3: bf16x3 MFMA GEMM (hh + hl + lh), 256x128 tile, 8 waves (4m x 2n),
// BK=32, 3-stage LDS ring + counted-vmcnt pipeline (R15, verbatim).
// ---------------------------------------------------------------------------
__global__ __launch_bounds__(512, 2)
void gemm_bf16x3p(const u16* __restrict__ Ah, const u16* __restrict__ Al,
                  const u16* __restrict__ Bh, const u16* __restrict__ Bl,
                  const float* __restrict__ bias, float* __restrict__ C) {
    extern __shared__ __align__(16) u16 smem[];
    u16* const sAh = smem;                          // [3][8192]
    u16* const sAl = smem + 3 * 8192;               // [3][8192]
    u16* const sBh = smem + 6 * 8192;               // [3][4096]
    u16* const sBl = smem + 6 * 8192 + 3 * 4096;    // [3][4096]

    const int tid  = threadIdx.x;
    const int m0   = blockIdx.y * 256;
    const int n0   = blockIdx.x * 128;
    const int lane = tid & 63;
    const int wave = tid >> 6;     // 0..7
    const int wm   = wave >> 1;    // 0..3 (64-row slab)
    const int wn   = wave & 1;     // 0..1 (64-col slab)

    const int cA0 = tid, cA1 = tid + 512, cB0 = tid;
#define OFFA(c) ((size_t)(m0 + ((c) >> 6) * 16 + ((c) & 15)) * K_DIM + (((c) >> 4) & 3) * 8)
#define OFFB(c) ((size_t)(n0 + ((c) >> 6) * 16 + ((c) & 15)) * K_DIM + (((c) >> 4) & 3) * 8)
    const size_t a0 = OFFA(cA0), a1 = OFFA(cA1), b0 = OFFB(cB0);
#undef OFFA
#undef OFFB

    // wave-uniform LDS dest offsets (u16) within a stage; HW adds lane*16B.
    const int lA0 = wave * 512;
    const int lA1 = 4096 + wave * 512;
    const int lB0 = wave * 512;

    f32x4 acc[4][4];
#pragma unroll
    for (int i = 0; i < 4; i++)
#pragma unroll
        for (int j = 0; j < 4; j++) acc[i][j] = (f32x4){0.f, 0.f, 0.f, 0.f};

#define STAGE(s, kc) do {                                                    \
        const int kn_ = (kc) * 32;                                           \
        GLDS16(Ah + a0 + kn_, sAh + (s) * 8192 + lA0);                       \
        GLDS16(Ah + a1 + kn_, sAh + (s) * 8192 + lA1);                       \
        GLDS16(Al + a0 + kn_, sAl + (s) * 8192 + lA0);                       \
        GLDS16(Al + a1 + kn_, sAl + (s) * 8192 + lA1);                       \
        GLDS16(Bh + b0 + kn_, sBh + (s) * 4096 + lB0);                       \
        GLDS16(Bl + b0 + kn_, sBl + (s) * 4096 + lB0);                       \
    } while (0)

#define COMPUTE(rs) do {                                                     \
        bf16x8 fah[4], fal[4], fbh[4], fbl[4];                               \
        _Pragma("unroll")                                                    \
        for (int ti = 0; ti < 4; ti++) {                                     \
            const int ta = wm * 4 + ti;                                      \
            fah[ti] = *(const bf16x8*)&sAh[(rs) * 8192 + (ta * 64 + lane) * 8]; \
            fal[ti] = *(const bf16x8*)&sAl[(rs) * 8192 + (ta * 64 + lane) * 8]; \
        }                                                                    \
        _Pragma("unroll")                                                    \
        for (int tj = 0; tj < 4; tj++) {                                     \
            const int tb = wn * 4 + tj;                                      \
            fbh[tj] = *(const bf16x8*)&sBh[(rs) * 4096 + (tb * 64 + lane) * 8]; \
            fbl[tj] = *(const bf16x8*)&sBl[(rs) * 4096 + (tb * 64 + lane) * 8]; \
        }                                                                    \
        __builtin_amdgcn_s_setprio(1);                                       \
        _Pragma("unroll")                                                    \
        for (int ti = 0; ti < 4; ti++)                                       \
        _Pragma("unroll")                                                    \
        for (int tj = 0; tj < 4; tj++) {                                     \
            acc[ti][tj] = __builtin_amdgcn_mfma_f32_16x16x32_bf16(           \
                fah[ti], fbh[tj], acc[ti][tj], 0, 0, 0);                     \
            acc[ti][tj] = __builtin_amdgcn_mfma_f32_16x16x32_bf16(           \
                fah[ti], fbl[tj], acc[ti][tj], 0, 0, 0);                     \
            acc[ti][tj] = __builtin_amdgcn_mfma_f32_16x16x32_bf16(           \
                fal[ti], fbh[tj], acc[ti][tj], 0, 0, 0);                     \
        }                                                                    \
        __builtin_amdgcn_s_setprio(0);                                       \
    } while (0)

#define SYNC(vm) do {                                                        \
        asm volatile("s_waitcnt vmcnt(" #vm ")" ::: "memory");               \
        __builtin_amdgcn_sched_barrier(0);                                   \
        __builtin_amdgcn_s_barrier();                                        \
        __builtin_amdgcn_sched_barrier(0);                                   \
    } while (0)

    // prologue: stages 0 and 1 in flight (12 outstanding loads)
    STAGE(0, 0);
    STAGE(1, 1);

    // main loop: kc = 0..62, unrolled x3 for static stage indices.
    // Invariant at top of kc: outstanding = stage kc remnants + stage kc+1's
    // six newest -> vmcnt(6) proves stage kc fully landed (in-order counter).
    for (int kcb = 0; kcb < 63; kcb += 3) {
        // kc = kcb: read stage 0, write stage 2
        SYNC(6);
        STAGE(2, kcb + 2);
        COMPUTE(0);
        // kc = kcb+1: read stage 1, write stage 0
        SYNC(6);
        STAGE(0, kcb + 3);
        COMPUTE(1);
        // kc = kcb+2: read stage 2, write stage 1
        SYNC(6);
        if (kcb + 4 < 64) STAGE(1, kcb + 4);
        COMPUTE(2);
    }
    // peeled kc = 63: read stage 0 (filled at kc=61); nothing newer in flight
    SYNC(0);
    COMPUTE(0);

#undef SYNC
#undef COMPUTE
#undef STAGE

#pragma unroll
    for (int tj = 0; tj < 4; tj++) {
        const int n  = n0 + wn * 64 + tj * 16 + (lane & 15);
        const float bv = bias[n];
#pragma unroll
        for (int ti = 0; ti < 4; ti++) {
            const int mbase = m0 + wm * 64 + ti * 16 + (lane >> 4) * 4;
#pragma unroll
            for (int r = 0; r < 4; r++)
                C[(size_t)(mbase + r) * N_DIM + n] = acc[ti][tj][r] + bv;
        }
    }
}

// ---------------------------------------------------------------------------
// k4: banded scan; flagged chains go to per-b worklists.
// ---------------------------------------------------------------------------
__global__ __launch_bounds__(256)
void lif_scan_band(float* __restrict__ buf, unsigned int* __restrict__ counters,
                   unsigned int* __restrict__ worklist) {
    const int idx = blockIdx.x * 256 + threadIdx.x;   // chain = b*2048 + o
    float mem = 0.0f;
    bool flag = false;
#pragma unroll
    for (int t = 0; t < T_STEPS; t++) {
        const size_t off = (size_t)t * NCHAIN + idx;
        mem = __fadd_rn(__fmul_rn(mem, DECAY_F32), buf[off]);
        const float d = __fsub_rn(mem, 1.0f);
        const bool spk = d > 0.0f;
        if (fabsf(d) < BAND) flag = true;
        buf[off] = spk ? 1.0f : 0.0f;
        if (spk) mem = __fsub_rn(mem, 1.0f);
    }
    if (flag) {
        const int b = idx >> 11, o = idx & 2047;
        const unsigned int p = atomicAdd(&counters[b], 1u);
        worklist[b * 2048 + p] = (unsigned int)o;
    }
}

// ---------------------------------------------------------------------------
// k5: b-grouped exact repair (R16 coalesced X-staging).
// ---------------------------------------------------------------------------
#define RG 16    // chains per group
#define RJ 4     // block-strides per b
#define BKR 64   // k-chunk (320 = 5*64: panel boundaries land on chunk edges)

__global__ __launch_bounds__(256)
void lif_repair2(const float* __restrict__ X, const float* __restrict__ W,
                 const float* __restrict__ bias,
                 const unsigned int* __restrict__ counters,
                 const unsigned int* __restrict__ worklist,
                 float* __restrict__ out) {
    __shared__ float sX[BKR][T_STEPS + 1];      // [k][t] 16.25 KiB
    __shared__ float sW[RG][BKR + 1];           // [o][k]  4.06 KiB
    __shared__ float scur[T_STEPS][RG + 1];
    __shared__ float sspk[T_STEPS][RG + 1];
    __shared__ int   so[RG];

    const int b = blockIdx.x / RJ;
    const int j = blockIdx.x % RJ;
    const unsigned int n_b = counters[b];
    if (n_b == 0) return;
    const int ngroups = (int)(n_b + RG - 1) / RG;

    const int tid = threadIdx.x;
    const int t   = tid & 63;
    const int oi  = tid >> 6;          // 0..3, owns o-slots 4*oi .. 4*oi+3

    for (int g = j; g < ngroups; g += RJ) {
        if (tid < RG) {
            const int slot = g * RG + tid;
            so[tid] = (slot < (int)n_b) ? (int)worklist[b * 2048 + slot] : -1;
        }
        __syncthreads();

        float Csum[4] = {0.f, 0.f, 0.f, 0.f};
        float P[4]    = {0.f, 0.f, 0.f, 0.f};

        for (int c = 0; c < K_DIM / BKR; c++) {
            if (c > 0 && (c % 5) == 0) {       // k = 320*j panel boundary
#pragma unroll
                for (int q = 0; q < 4; q++) {
                    Csum[q] = __fadd_rn(Csum[q], P[q]);
                    P[q] = 0.f;
                }
            }
            const int k0 = c * BKR;
            // stage X chunk: 64 t x 64 k; lanes 4i..4i+3 read row i's 256 B
            {
                const int ts = tid >> 2;            // 0..63 row
                const int kq = (tid & 3) * 16;      // 0..48 col quarter
                const float* src = &X[(size_t)(ts * BATCH + b) * K_DIM + k0 + kq];
#pragma unroll
                for (int q = 0; q < 4; q++) {
                    const float4 v = *(const float4*)(src + q * 4);
                    sX[kq + q * 4 + 0][ts] = v.x;
                    sX[kq + q * 4 + 1][ts] = v.y;
                    sX[kq + q * 4 + 2][ts] = v.z;
                    sX[kq + q * 4 + 3][ts] = v.w;
                }
            }
            // stage W chunk: 16 o x 64 k, 1 float4 per thread
            {
                const int wo  = tid >> 4;          // 0..15
                const int wkq = (tid & 15) * 4;    // 0..60
                const int o   = so[wo];
                float4 v = {0.f, 0.f, 0.f, 0.f};
                if (o >= 0) v = *(const float4*)&W[(size_t)o * K_DIM + k0 + wkq];
                sW[wo][wkq + 0] = v.x; sW[wo][wkq + 1] = v.y;
                sW[wo][wkq + 2] = v.z; sW[wo][wkq + 3] = v.w;
            }
            __syncthreads();
            // exact sequential-k FMA, 4 independent chains (ILP)
#pragma unroll 8
            for (int k = 0; k < BKR; k++) {
                const float xv = sX[k][t];
#pragma unroll
                for (int q = 0; q < 4; q++)
                    P[q] = fmaf(xv, sW[oi * 4 + q][k], P[q]);
            }
            __syncthreads();
        }
#pragma unroll
        for (int q = 0; q < 4; q++) {
            Csum[q] = __fadd_rn(Csum[q], P[q]);    // final 128-elem panel
            const int o = so[oi * 4 + q];
            scur[t][oi * 4 + q] = (o >= 0) ? __fadd_rn(Csum[q], bias[o]) : 0.f;
        }
        __syncthreads();
        if (tid < RG && so[tid] >= 0) {
            float mem = 0.0f;
            for (int tt = 0; tt < T_STEPS; tt++) {
                mem = __fadd_rn(__fmul_rn(mem, DECAY_F32), scur[tt][tid]);
                const float d = __fsub_rn(mem, 1.0f);
                const bool spk = d > 0.0f;
                sspk[tt][tid] = spk ? 1.0f : 0.0f;
                if (spk) mem = __fsub_rn(mem, 1.0f);
            }
        }
        __syncthreads();
#pragma unroll
        for (int q = 0; q < 4; q++) {
            const int o = so[oi * 4 + q];
            if (o >= 0)
                out[(size_t)t * NCHAIN + (size_t)b * N_DIM + o] = sspk[t][oi * 4 + q];
        }
        __syncthreads();
    }
}

// ---------------------------------------------------------------------------
// FALLBACK (R8, known-passing, ws-free).
// ---------------------------------------------------------------------------
__global__ __launch_bounds__(256)
void lif_openblas_q320(const float* __restrict__ X, const float* __restrict__ W,
                       const float* __restrict__ bias, float* __restrict__ out) {
    __shared__ float As[16][T_STEPS + 4];
    __shared__ float Ws[16][64 + 4];
    __shared__ float curbuf[T_STEPS][64 + 1];
    const int tid = threadIdx.x;
    const int o0 = blockIdx.x * 64, b0 = blockIdx.y;
    const int tm = (tid & 15) * 4, tn = (tid >> 4) * 4;
    float Csum[4][4], Pacc[4][4];
#pragma unroll
    for (int i = 0; i < 4; i++)
#pragma unroll
        for (int j = 0; j < 4; j++) { Csum[i][j] = 0.f; Pacc[i][j] = 0.f; }
    for (int c = 0; c < K_DIM / 16; c++) {
        if (c > 0 && (c % 20) == 0) {
#pragma unroll
            for (int i = 0; i < 4; i++)
#pragma unroll
                for (int j = 0; j < 4; j++) {
                    Csum[i][j] = __fadd_rn(Csum[i][j], Pacc[i][j]);
                    Pacc[i][j] = 0.f;
                }
        }
        const int k0 = c * 16;
        {
            const int t = tid >> 2, kq = (tid & 3) * 4;
            const float4 av = *(const float4*)&X[(size_t)(t * BATCH + b0) * K_DIM + k0 + kq];
            As[kq + 0][t] = av.x; As[kq + 1][t] = av.y;
            As[kq + 2][t] = av.z; As[kq + 3][t] = av.w;
            const float4 wv = *(const float4*)&W[(size_t)(o0 + t) * K_DIM + k0 + kq];
            Ws[kq + 0][t] = wv.x; Ws[kq + 1][t] = wv.y;
            Ws[kq + 2][t] = wv.z; Ws[kq + 3][t] = wv.w;
        }
        __syncthreads();
#pragma unroll
        for (int k = 0; k < 16; k++) {
            float a[4], w[4];
#pragma unroll
            for (int i = 0; i < 4; i++) a[i] = As[k][tm + i];
#pragma unroll
            for (int j = 0; j < 4; j++) w[j] = Ws[k][tn + j];
#pragma unroll
            for (int i = 0; i < 4; i++)
#pragma unroll
                for (int j = 0; j < 4; j++) Pacc[i][j] = fmaf(a[i], w[j], Pacc[i][j]);
        }
        __syncthreads();
    }
#pragma unroll
    for (int i = 0; i < 4; i++)
#pragma unroll
        for (int j = 0; j < 4; j++)
            curbuf[tm + i][tn + j] =
                __fadd_rn(__fadd_rn(Csum[i][j], Pacc[i][j]), bias[o0 + tn + j]);
    __syncthreads();
    if (tid < 64) {
        float mem = 0.0f;
#pragma unroll
        for (int t = 0; t < T_STEPS; t++) {
            mem = __fadd_rn(__fmul_rn(mem, DECAY_F32), curbuf[t][tid]);
            const float d = __fsub_rn(mem, 1.0f);
            const bool spk = d > 0.0f;
            out[(size_t)t * NCHAIN + (size_t)b0 * N_DIM + o0 + tid] = spk ? 1.0f : 0.0f;
            if (spk) mem = __fsub_rn(mem, 1.0f);
        }
    }
}

extern "C" void kernel_launch(void* const* d_in, const int* in_sizes, int n_in,
                              void* d_out, int out_size, void* d_ws, size_t ws_size,
                              hipStream_t stream) {
    const float* x = nullptr; const float* W = nullptr; const float* bias = nullptr;
    for (int i = 0; i < n_in; i++) {
        if      (in_sizes[i] == M_DIM * K_DIM) x    = (const float*)d_in[i];
        else if (in_sizes[i] == N_DIM * K_DIM) W    = (const float*)d_in[i];
        else if (in_sizes[i] == N_DIM)         bias = (const float*)d_in[i];
    }
    if (!x)    x    = (const float*)d_in[0];
    if (!W)    W    = (const float*)d_in[1];
    if (!bias) bias = (const float*)d_in[2];
    float* out = (float*)d_out;

    // workspace layout
    const size_t off_cnt = 0;                                     // 128 u32
    const size_t off_wl  = 512;                                   // 128*2048 u32
    const size_t off_Ah  = off_wl + (size_t)128 * 2048 * 4;       // 1049088
    const size_t szA     = (size_t)M_DIM * K_DIM * 2;             // 32 MiB
    const size_t szW     = (size_t)N_DIM * K_DIM * 2;             //  8 MiB
    const size_t off_Al  = off_Ah + szA;
    const size_t off_Wh  = off_Al + szA;
    const size_t off_Wl  = off_Wh + szW;
    const size_t need    = off_Wl + szW;

    if (ws_size < need) {
        dim3 grid(N_DIM / 64, BATCH);
        lif_openblas_q320<<<grid, 256, 0, stream>>>(x, W, bias, out);
        return;
    }

    char* ws = (char*)d_ws;
    unsigned int* counters = (unsigned int*)(ws + off_cnt);
    unsigned int* worklist = (unsigned int*)(ws + off_wl);
    u16* Ah = (u16*)(ws + off_Ah);
    u16* Al = (u16*)(ws + off_Al);
    u16* Wh = (u16*)(ws + off_Wh);
    u16* Wl = (u16*)(ws + off_Wl);

    split_bf16<<<(M_DIM * K_DIM / 4 + N_DIM * K_DIM / 4) / 256, 256, 0, stream>>>(
        x, W, Ah, Al, Wh, Wl, counters);
    dim3 ggrid(N_DIM / 128, M_DIM / 256);   // (16, 32)
    gemm_bf16x3p<<<ggrid, 512, 147456, stream>>>(Ah, Al, Wh, Wl, bias, out);
    lif_scan_band<<<NCHAIN / 256, 256, 0, stream>>>(out, counters, worklist);
    lif_repair2<<<128 * RJ, 256, 0, stream>>>(x, W, bias, counters, worklist, out);
}

// Round 9
// 456.874 us; speedup vs baseline: 1.3654x; 1.0302x over previous
//
#include <hip/hip_runtime.h>
#include <hip/hip_bf16.h>
#include <math.h>

// ---------------------------------------------------------------------------
// LIF layer, round 19: R18 pipeline + (1) XCD-chunked block swizzle on the
// GEMM (T1; 512 blocks, 512%8==0 -> bijective; A-panels become XCD-L2
// resident, FETCH 278MB -> ~unique), (2) scan vectorized 4 chains/thread
// (float4, 16B/lane; scalar 4B loads were the suspected latency-bound tail),
// (3) split 8 elems/thread (2x float4 in, uint4 out).
//
// R18 post-mortem: BAND 5e-4->2e-4 moved wall only -12us => repair ~20us,
// NOT the tail driver. Gemm runs 1 block/CU (144KB LDS) -> no inter-block
// overlap; stall-bound with 3.5x overfetch. Repair & gemm math untouched;
// scan per-chain numerics identical -> absmax 0.0.
// ---------------------------------------------------------------------------

typedef unsigned short u16;
typedef __attribute__((ext_vector_type(8))) short bf16x8;
typedef __attribute__((ext_vector_type(4))) float f32x4;

constexpr int T_STEPS = 64;
constexpr int BATCH   = 128;
constexpr int K_DIM   = 2048;
constexpr int N_DIM   = 2048;
constexpr int M_DIM   = T_STEPS * BATCH;      // 8192
constexpr int NCHAIN  = BATCH * N_DIM;        // 262144

constexpr float DECAY_F32 = (float)0.6065306597126334;
constexpr float BAND      = 2e-4f;            // error tail ~6e-5, 3.3x margin

#define GLDS16(g, l) __builtin_amdgcn_global_load_lds(                       \
    (const __attribute__((address_space(1))) void*)(g),                      \
    (__attribute__((address_space(3))) void*)(l), 16, 0, 0)

// ---------------------------------------------------------------------------
// k2: Dekker split f32 -> bf16 hi/lo, 8 elems/thread; block 0 also zeroes
// the 128 per-b worklist counters.
// ---------------------------------------------------------------------------
__global__ __launch_bounds__(256)
void split_bf16(const float* __restrict__ X, const float* __restrict__ W,
                u16* __restrict__ Ah, u16* __restrict__ Al,
                u16* __restrict__ Wh, u16* __restrict__ Wl,
                unsigned int* __restrict__ counters) {
    if (blockIdx.x == 0 && threadIdx.x < 128) counters[threadIdx.x] = 0u;

    constexpr int NA8 = (M_DIM * K_DIM) / 8;
    constexpr int NW8 = (N_DIM * K_DIM) / 8;
    const int i = blockIdx.x * 256 + threadIdx.x;
    const float* src; u16* dh; u16* dl; int base;
    if (i < NA8)            { src = X; dh = Ah; dl = Al; base = i; }
    else if (i < NA8 + NW8) { src = W; dh = Wh; dl = Wl; base = i - NA8; }
    else return;

    const float4 v0 = *(const float4*)(src + (size_t)base * 8);
    const float4 v1 = *(const float4*)(src + (size_t)base * 8 + 4);
    const float f[8] = {v0.x, v0.y, v0.z, v0.w, v1.x, v1.y, v1.z, v1.w};
    unsigned int hp[4], lp[4];
#pragma unroll
    for (int q = 0; q < 8; q += 2) {
        u16 hh[2], ll[2];
#pragma unroll
        for (int e = 0; e < 2; e++) {
            __hip_bfloat16 hb = __float2bfloat16(f[q + e]);
            const float hf = __bfloat162float(hb);
            __hip_bfloat16 lb = __float2bfloat16(f[q + e] - hf);
            hh[e] = *(u16*)&hb;
            ll[e] = *(u16*)&lb;
        }
        hp[q >> 1] = (unsigned int)hh[0] | ((unsigned int)hh[1] << 16);
        lp[q >> 1] = (unsigned int)ll[0] | ((unsigned int)ll[1] << 16);
    }
    *(uint4*)(dh + (size_t)base * 8) = make_uint4(hp[0], hp[1], hp[2], hp[3]);
    *(uint4*)(dl + (size_t)base * 8) = make_uint4(lp[0], lp[1], lp[2], lp[3]);
}

// ---------------------------------------------------------------------------
// k3: bf16x3 MFMA GEMM (hh + hl + lh), 256x128 tile, 8 waves (4m x 2n),
// BK=32, 3-stage LDS ring + counted-vmcnt pipeline (R15) + XCD-chunked
// block swizzle: launched-bid i executes tile (i%8)*64 + i/8, so each XCD
// (round-robin dispatch) owns 64 consecutive tiles = 4 A-panel rows x all
// 16 n-columns -> A-panel L2-resident per XCD.
// ---------------------------------------------------------------------------
__global__ __launch_bounds__(512, 2)
void gemm_bf16x3p(const u16* __restrict__ Ah, const u16* __restrict__ Al,
                  const u16* __restrict__ Bh, const u16* __restrict__ Bl,
                  const float* __restrict__ bias, float* __restrict__ C) {
    extern __shared__ __align__(16) u16 smem[];
    u16* const sAh = smem;                          // [3][8192]
    u16* const sAl = smem + 3 * 8192;               // [3][8192]
    u16* const sBh = smem + 6 * 8192;               // [3][4096]
    u16* const sBl = smem + 6 * 8192 + 3 * 4096;    // [3][4096]

    const int tid  = threadIdx.x;
    // XCD-chunked swizzle (bijective: 512 % 8 == 0)
    const int orig = blockIdx.x + gridDim.x * blockIdx.y;   // 0..511
    const int wg   = (orig & 7) * 64 + (orig >> 3);
    const int m0   = (wg >> 4) * 256;   // wg / 16 -> A-panel row
    const int n0   = (wg & 15) * 128;   // wg % 16 -> B column
    const int lane = tid & 63;
    const int wave = tid >> 6;     // 0..7
    const int wm   = wave >> 1;    // 0..3 (64-row slab)
    const int wn   = wave & 1;     // 0..1 (64-col slab)

    const int cA0 = tid, cA1 = tid + 512, cB0 = tid;
#define OFFA(c) ((size_t)(m0 + ((c) >> 6) * 16 + ((c) & 15)) * K_DIM + (((c) >> 4) & 3) * 8)
#define OFFB(c) ((size_t)(n0 + ((c) >> 6) * 16 + ((c) & 15)) * K_DIM + (((c) >> 4) & 3) * 8)
    const size_t a0 = OFFA(cA0), a1 = OFFA(cA1), b0 = OFFB(cB0);
#undef OFFA
#undef OFFB

    // wave-uniform LDS dest offsets (u16) within a stage; HW adds lane*16B.
    const int lA0 = wave * 512;
    const int lA1 = 4096 + wave * 512;
    const int lB0 = wave * 512;

    f32x4 acc[4][4];
#pragma unroll
    for (int i = 0; i < 4; i++)
#pragma unroll
        for (int j = 0; j < 4; j++) acc[i][j] = (f32x4){0.f, 0.f, 0.f, 0.f};

#define STAGE(s, kc) do {                                                    \
        const int kn_ = (kc) * 32;                                           \
        GLDS16(Ah + a0 + kn_, sAh + (s) * 8192 + lA0);                       \
        GLDS16(Ah + a1 + kn_, sAh + (s) * 8192 + lA1);                       \
        GLDS16(Al + a0 + kn_, sAl + (s) * 8192 + lA0);                       \
        GLDS16(Al + a1 + kn_, sAl + (s) * 8192 + lA1);                       \
        GLDS16(Bh + b0 + kn_, sBh + (s) * 4096 + lB0);                       \
        GLDS16(Bl + b0 + kn_, sBl + (s) * 4096 + lB0);                       \
    } while (0)

#define COMPUTE(rs) do {                                                     \
        bf16x8 fah[4], fal[4], fbh[4], fbl[4];                               \
        _Pragma("unroll")                                                    \
        for (int ti = 0; ti < 4; ti++) {                                     \
            const int ta = wm * 4 + ti;                                      \
            fah[ti] = *(const bf16x8*)&sAh[(rs) * 8192 + (ta * 64 + lane) * 8]; \
            fal[ti] = *(const bf16x8*)&sAl[(rs) * 8192 + (ta * 64 + lane) * 8]; \
        }                                                                    \
        _Pragma("unroll")                                                    \
        for (int tj = 0; tj < 4; tj++) {                                     \
            const int tb = wn * 4 + tj;                                      \
            fbh[tj] = *(const bf16x8*)&sBh[(rs) * 4096 + (tb * 64 + lane) * 8]; \
            fbl[tj] = *(const bf16x8*)&sBl[(rs) * 4096 + (tb * 64 + lane) * 8]; \
        }                                                                    \
        __builtin_amdgcn_s_setprio(1);                                       \
        _Pragma("unroll")                                                    \
        for (int ti = 0; ti < 4; ti++)                                       \
        _Pragma("unroll")                                                    \
        for (int tj = 0; tj < 4; tj++) {                                     \
            acc[ti][tj] = __builtin_amdgcn_mfma_f32_16x16x32_bf16(           \
                fah[ti], fbh[tj], acc[ti][tj], 0, 0, 0);                     \
            acc[ti][tj] = __builtin_amdgcn_mfma_f32_16x16x32_bf16(           \
                fah[ti], fbl[tj], acc[ti][tj], 0, 0, 0);                     \
            acc[ti][tj] = __builtin_amdgcn_mfma_f32_16x16x32_bf16(           \
                fal[ti], fbh[tj], acc[ti][tj], 0, 0, 0);                     \
        }                                                                    \
        __builtin_amdgcn_s_setprio(0);                                       \
    } while (0)

#define SYNC(vm) do {                                                        \
        asm volatile("s_waitcnt vmcnt(" #vm ")" ::: "memory");               \
        __builtin_amdgcn_sched_barrier(0);                                   \
        __builtin_amdgcn_s_barrier();                                        \
        __builtin_amdgcn_sched_barrier(0);                                   \
    } while (0)

    // prologue: stages 0 and 1 in flight (12 outstanding loads)
    STAGE(0, 0);
    STAGE(1, 1);

    // main loop: kc = 0..62, unrolled x3 for static stage indices.
    for (int kcb = 0; kcb < 63; kcb += 3) {
        SYNC(6);
        STAGE(2, kcb + 2);
        COMPUTE(0);
        SYNC(6);
        STAGE(0, kcb + 3);
        COMPUTE(1);
        SYNC(6);
        if (kcb + 4 < 64) STAGE(1, kcb + 4);
        COMPUTE(2);
    }
    // peeled kc = 63
    SYNC(0);
    COMPUTE(0);

#undef SYNC
#undef COMPUTE
#undef STAGE

#pragma unroll
    for (int tj = 0; tj < 4; tj++) {
        const int n  = n0 + wn * 64 + tj * 16 + (lane & 15);
        const float bv = bias[n];
#pragma unroll
        for (int ti = 0; ti < 4; ti++) {
            const int mbase = m0 + wm * 64 + ti * 16 + (lane >> 4) * 4;
#pragma unroll
            for (int r = 0; r < 4; r++)
                C[(size_t)(mbase + r) * N_DIM + n] = acc[ti][tj][r] + bv;
        }
    }
}

// ---------------------------------------------------------------------------
// k4: banded scan, 4 chains/thread (float4 in/out, 16B/lane). Per-chain
// numerics identical to the scalar version.
// ---------------------------------------------------------------------------
__global__ __launch_bounds__(256)
void lif_scan_band4(float* __restrict__ buf, unsigned int* __restrict__ counters,
                    unsigned int* __restrict__ worklist) {
    const int idx = (blockIdx.x * 256 + threadIdx.x) * 4;   // chain base
    float mem[4]  = {0.f, 0.f, 0.f, 0.f};
    bool  flag[4] = {false, false, false, false};
#pragma unroll
    for (int t = 0; t < T_STEPS; t++) {
        const size_t off = (size_t)t * NCHAIN + idx;
        const float4 v = *(const float4*)(buf + off);
        const float c[4] = {v.x, v.y, v.z, v.w};
        float s[4];
#pragma unroll
        for (int q = 0; q < 4; q++) {
            mem[q] = __fadd_rn(__fmul_rn(mem[q], DECAY_F32), c[q]);
            const float d = __fsub_rn(mem[q], 1.0f);
            const bool spk = d > 0.0f;
            if (fabsf(d) < BAND) flag[q] = true;
            s[q] = spk ? 1.0f : 0.0f;
            if (spk) mem[q] = __fsub_rn(mem[q], 1.0f);
        }
        *(float4*)(buf + off) = make_float4(s[0], s[1], s[2], s[3]);
    }
    const int b = idx >> 11;   // 4 consecutive chains share b (idx % 4 == 0)
#pragma unroll
    for (int q = 0; q < 4; q++) {
        if (flag[q]) {
            const unsigned int p = atomicAdd(&counters[b], 1u);
            worklist[b * 2048 + p] = (unsigned int)((idx + q) & 2047);
        }
    }
}

// ---------------------------------------------------------------------------
// k5: b-grouped exact repair (R16 coalesced X-staging). Unchanged.
// ---------------------------------------------------------------------------
#define RG 16    // chains per group
#define RJ 4     // block-strides per b
#define BKR 64   // k-chunk (320 = 5*64: panel boundaries land on chunk edges)

__global__ __launch_bounds__(256)
void lif_repair2(const float* __restrict__ X, const float* __restrict__ W,
                 const float* __restrict__ bias,
                 const unsigned int* __restrict__ counters,
                 const unsigned int* __restrict__ worklist,
                 float* __restrict__ out) {
    __shared__ float sX[BKR][T_STEPS + 1];      // [k][t] 16.25 KiB
    __shared__ float sW[RG][BKR + 1];           // [o][k]  4.06 KiB
    __shared__ float scur[T_STEPS][RG + 1];
    __shared__ float sspk[T_STEPS][RG + 1];
    __shared__ int   so[RG];

    const int b = blockIdx.x / RJ;
    const int j = blockIdx.x % RJ;
    const unsigned int n_b = counters[b];
    if (n_b == 0) return;
    const int ngroups = (int)(n_b + RG - 1) / RG;

    const int tid = threadIdx.x;
    const int t   = tid & 63;
    const int oi  = tid >> 6;          // 0..3, owns o-slots 4*oi .. 4*oi+3

    for (int g = j; g < ngroups; g += RJ) {
        if (tid < RG) {
            const int slot = g * RG + tid;
            so[tid] = (slot < (int)n_b) ? (int)worklist[b * 2048 + slot] : -1;
        }
        __syncthreads();

        float Csum[4] = {0.f, 0.f, 0.f, 0.f};
        float P[4]    = {0.f, 0.f, 0.f, 0.f};

        for (int c = 0; c < K_DIM / BKR; c++) {
            if (c > 0 && (c % 5) == 0) {       // k = 320*j panel boundary
#pragma unroll
                for (int q = 0; q < 4; q++) {
                    Csum[q] = __fadd_rn(Csum[q], P[q]);
                    P[q] = 0.f;
                }
            }
            const int k0 = c * BKR;
            // stage X chunk: 64 t x 64 k; lanes 4i..4i+3 read row i's 256 B
            {
                const int ts = tid >> 2;            // 0..63 row
                const int kq = (tid & 3) * 16;      // 0..48 col quarter
                const float* src = &X[(size_t)(ts * BATCH + b) * K_DIM + k0 + kq];
#pragma unroll
                for (int q = 0; q < 4; q++) {
                    const float4 v = *(const float4*)(src + q * 4);
                    sX[kq + q * 4 + 0][ts] = v.x;
                    sX[kq + q * 4 + 1][ts] = v.y;
                    sX[kq + q * 4 + 2][ts] = v.z;
                    sX[kq + q * 4 + 3][ts] = v.w;
                }
            }
            // stage W chunk: 16 o x 64 k, 1 float4 per thread
            {
                const int wo  = tid >> 4;          // 0..15
                const int wkq = (tid & 15) * 4;    // 0..60
                const int o   = so[wo];
                float4 v = {0.f, 0.f, 0.f, 0.f};
                if (o >= 0) v = *(const float4*)&W[(size_t)o * K_DIM + k0 + wkq];
                sW[wo][wkq + 0] = v.x; sW[wo][wkq + 1] = v.y;
                sW[wo][wkq + 2] = v.z; sW[wo][wkq + 3] = v.w;
            }
            __syncthreads();
            // exact sequential-k FMA, 4 independent chains (ILP)
#pragma unroll 8
            for (int k = 0; k < BKR; k++) {
                const float xv = sX[k][t];
#pragma unroll
                for (int q = 0; q < 4; q++)
                    P[q] = fmaf(xv, sW[oi * 4 + q][k], P[q]);
            }
            __syncthreads();
        }
#pragma unroll
        for (int q = 0; q < 4; q++) {
            Csum[q] = __fadd_rn(Csum[q], P[q]);    // final 128-elem panel
            const int o = so[oi * 4 + q];
            scur[t][oi * 4 + q] = (o >= 0) ? __fadd_rn(Csum[q], bias[o]) : 0.f;
        }
        __syncthreads();
        if (tid < RG && so[tid] >= 0) {
            float mem = 0.0f;
            for (int tt = 0; tt < T_STEPS; tt++) {
                mem = __fadd_rn(__fmul_rn(mem, DECAY_F32), scur[tt][tid]);
                const float d = __fsub_rn(mem, 1.0f);
                const bool spk = d > 0.0f;
                sspk[tt][tid] = spk ? 1.0f : 0.0f;
                if (spk) mem = __fsub_rn(mem, 1.0f);
            }
        }
        __syncthreads();
#pragma unroll
        for (int q = 0; q < 4; q++) {
            const int o = so[oi * 4 + q];
            if (o >= 0)
                out[(size_t)t * NCHAIN + (size_t)b * N_DIM + o] = sspk[t][oi * 4 + q];
        }
        __syncthreads();
    }
}

// ---------------------------------------------------------------------------
// FALLBACK (R8, known-passing, ws-free).
// ---------------------------------------------------------------------------
__global__ __launch_bounds__(256)
void lif_openblas_q320(const float* __restrict__ X, const float* __restrict__ W,
                       const float* __restrict__ bias, float* __restrict__ out) {
    __shared__ float As[16][T_STEPS + 4];
    __shared__ float Ws[16][64 + 4];
    __shared__ float curbuf[T_STEPS][64 + 1];
    const int tid = threadIdx.x;
    const int o0 = blockIdx.x * 64, b0 = blockIdx.y;
    const int tm = (tid & 15) * 4, tn = (tid >> 4) * 4;
    float Csum[4][4], Pacc[4][4];
#pragma unroll
    for (int i = 0; i < 4; i++)
#pragma unroll
        for (int j = 0; j < 4; j++) { Csum[i][j] = 0.f; Pacc[i][j] = 0.f; }
    for (int c = 0; c < K_DIM / 16; c++) {
        if (c > 0 && (c % 20) == 0) {
#pragma unroll
            for (int i = 0; i < 4; i++)
#pragma unroll
                for (int j = 0; j < 4; j++) {
                    Csum[i][j] = __fadd_rn(Csum[i][j], Pacc[i][j]);
                    Pacc[i][j] = 0.f;
                }
        }
        const int k0 = c * 16;
        {
            const int t = tid >> 2, kq = (tid & 3) * 4;
            const float4 av = *(const float4*)&X[(size_t)(t * BATCH + b0) * K_DIM + k0 + kq];
            As[kq + 0][t] = av.x; As[kq + 1][t] = av.y;
            As[kq + 2][t] = av.z; As[kq + 3][t] = av.w;
            const float4 wv = *(const float4*)&W[(size_t)(o0 + t) * K_DIM + k0 + kq];
            Ws[kq + 0][t] = wv.x; Ws[kq + 1][t] = wv.y;
            Ws[kq + 2][t] = wv.z; Ws[kq + 3][t] = wv.w;
        }
        __syncthreads();
#pragma unroll
        for (int k = 0; k < 16; k++) {
            float a[4], w[4];
#pragma unroll
            for (int i = 0; i < 4; i++) a[i] = As[k][tm + i];
#pragma unroll
            for (int j = 0; j < 4; j++) w[j] = Ws[k][tn + j];
#pragma unroll
            for (int i = 0; i < 4; i++)
#pragma unroll
                for (int j = 0; j < 4; j++) Pacc[i][j] = fmaf(a[i], w[j], Pacc[i][j]);
        }
        __syncthreads();
    }
#pragma unroll
    for (int i = 0; i < 4; i++)
#pragma unroll
        for (int j = 0; j < 4; j++)
            curbuf[tm + i][tn + j] =
                __fadd_rn(__fadd_rn(Csum[i][j], Pacc[i][j]), bias[o0 + tn + j]);
    __syncthreads();
    if (tid < 64) {
        float mem = 0.0f;
#pragma unroll
        for (int t = 0; t < T_STEPS; t++) {
            mem = __fadd_rn(__fmul_rn(mem, DECAY_F32), curbuf[t][tid]);
            const float d = __fsub_rn(mem, 1.0f);
            const bool spk = d > 0.0f;
            out[(size_t)t * NCHAIN + (size_t)b0 * N_DIM + o0 + tid] = spk ? 1.0f : 0.0f;
            if (spk) mem = __fsub_rn(mem, 1.0f);
        }
    }
}

extern "C" void kernel_launch(void* const* d_in, const int* in_sizes, int n_in,
                              void* d_out, int out_size, void* d_ws, size_t ws_size,
                              hipStream_t stream) {
    const float* x = nullptr; const float* W = nullptr; const float* bias = nullptr;
    for (int i = 0; i < n_in; i++) {
        if      (in_sizes[i] == M_DIM * K_DIM) x    = (const float*)d_in[i];
        else if (in_sizes[i] == N_DIM * K_DIM) W    = (const float*)d_in[i];
        else if (in_sizes[i] == N_DIM)         bias = (const float*)d_in[i];
    }
    if (!x)    x    = (const float*)d_in[0];
    if (!W)    W    = (const float*)d_in[1];
    if (!bias) bias = (const float*)d_in[2];
    float* out = (float*)d_out;

    // workspace layout
    const size_t off_cnt = 0;                                     // 128 u32
    const size_t off_wl  = 512;                                   // 128*2048 u32
    const size_t off_Ah  = off_wl + (size_t)128 * 2048 * 4;       // 1049088
    const size_t szA     = (size_t)M_DIM * K_DIM * 2;             // 32 MiB
    const size_t szW     = (size_t)N_DIM * K_DIM * 2;             //  8 MiB
    const size_t off_Al  = off_Ah + szA;
    const size_t off_Wh  = off_Al + szA;
    const size_t off_Wl  = off_Wh + szW;
    const size_t need    = off_Wl + szW;

    if (ws_size < need) {
        dim3 grid(N_DIM / 64, BATCH);
        lif_openblas_q320<<<grid, 256, 0, stream>>>(x, W, bias, out);
        return;
    }

    char* ws = (char*)d_ws;
    unsigned int* counters = (unsigned int*)(ws + off_cnt);
    unsigned int* worklist = (unsigned int*)(ws + off_wl);
    u16* Ah = (u16*)(ws + off_Ah);
    u16* Al = (u16*)(ws + off_Al);
    u16* Wh = (u16*)(ws + off_Wh);
    u16* Wl = (u16*)(ws + off_Wl);

    split_bf16<<<(M_DIM * K_DIM / 8 + N_DIM * K_DIM / 8) / 256, 256, 0, stream>>>(
        x, W, Ah, Al, Wh, Wl, counters);
    dim3 ggrid(N_DIM / 128, M_DIM / 256);   // (16, 32)
    gemm_bf16x3p<<<ggrid, 512, 147456, stream>>>(Ah, Al, Wh, Wl, bias, out);
    lif_scan_band4<<<NCHAIN / 1024, 256, 0, stream>>>(out, counters, worklist);
    lif_repair2<<<128 * RJ, 256, 0, stream>>>(x, W, bias, counters, worklist, out);
}

// Round 10
// 443.978 us; speedup vs baseline: 1.4051x; 1.0290x over previous
//
#include <hip/hip_runtime.h>
#include <hip/hip_bf16.h>
#include <math.h>

// ---------------------------------------------------------------------------
// LIF layer, round 20: SPLIT KERNEL DELETED — Dekker bf16 hi/lo split fused
// into the GEMM staging (global f32 -> regs -> convert -> ds_write, 2-slot
// ring, write-one-ahead, counted vmcnt). Scan/repair unchanged from R19.
//
// R19 post-mortem: XCD swizzle halved FETCH (278->164MB) with ZERO gemm time
// change -> gemm is not latency/BW/conflict bound; at 926 TF effective it
// sits at the documented plain-HIP ceiling for this structure class. Tail
// (234us) is the target: split was ~240MB traffic + a launch (~50us).
// Fused staging: same bytes loaded (8 f32 = 32B == 16B hi + 16B lo bf16),
// same element indexing (coalescing/L2 unchanged), conversion VALU hides in
// the gemm's existing stall; LDS contents bitwise identical -> C identical.
//
// Ring invariants, body(kc), kc = 0..63:
//   barrier                      // slot (kc)%2 written block-wide (prev step)
//   GLOAD(kc+2)                  // 6 global_load_dwordx4 (skip if >63)
//   vmcnt(6)                     // G(kc+1) landed (leave newest 6 = G(kc+2))
//   CONVWRITE slot (kc+1)%2      // Dekker + 6 ds_write_b128
//   lgkmcnt(0)                   // my writes done before next barrier
//   COMPUTE slot kc%2            // 16 ds_read_b128 + 48 MFMA (compiler waits)
// Readers of a slot finish before the barrier preceding its rewrite.
// ---------------------------------------------------------------------------

typedef unsigned short u16;
typedef __attribute__((ext_vector_type(8))) short bf16x8;
typedef __attribute__((ext_vector_type(4))) float f32x4;

constexpr int T_STEPS = 64;
constexpr int BATCH   = 128;
constexpr int K_DIM   = 2048;
constexpr int N_DIM   = 2048;
constexpr int M_DIM   = T_STEPS * BATCH;      // 8192
constexpr int NCHAIN  = BATCH * N_DIM;        // 262144

constexpr float DECAY_F32 = (float)0.6065306597126334;
constexpr float BAND      = 2e-4f;            // error tail ~6e-5, 3.3x margin

// ---------------------------------------------------------------------------
// k3: fused split+GEMM. bf16x3 (hh+hl+lh), 256x128 tile, 8 waves (4m x 2n),
// BK=32, 2-slot LDS ring (96 KiB), XCD-chunked swizzle, counted vmcnt.
// Block 0 also zeroes the 128 per-b worklist counters.
// ---------------------------------------------------------------------------
__global__ __launch_bounds__(512, 2)
void gemm_bf16x3f(const float* __restrict__ X, const float* __restrict__ W,
                  const float* __restrict__ bias, float* __restrict__ C,
                  unsigned int* __restrict__ counters) {
    extern __shared__ __align__(16) u16 smem[];
    u16* const sAh = smem;                          // [2][8192]
    u16* const sAl = smem + 2 * 8192;               // [2][8192]
    u16* const sBh = smem + 4 * 8192;               // [2][4096]
    u16* const sBl = smem + 4 * 8192 + 2 * 4096;    // [2][4096]

    const int tid  = threadIdx.x;
    const int orig = blockIdx.x + gridDim.x * blockIdx.y;   // 0..511
    if (orig == 0 && tid < 128) counters[tid] = 0u;

    // XCD-chunked swizzle (bijective: 512 % 8 == 0)
    const int wg   = (orig & 7) * 64 + (orig >> 3);
    const int m0   = (wg >> 4) * 256;
    const int n0   = (wg & 15) * 128;
    const int lane = tid & 63;
    const int wave = tid >> 6;     // 0..7
    const int wm   = wave >> 1;    // 0..3 (64-row slab)
    const int wn   = wave & 1;     // 0..1 (64-col slab)

    // staging entry: row (tid>>6)*16 + (tid&15), k-slot ((tid>>4)&3)*8 elems
    const int row_e = (tid >> 6) * 16 + (tid & 15);
    const int ks_e  = ((tid >> 4) & 3) * 8;
    const size_t a0f = (size_t)(m0 + row_e) * K_DIM + ks_e;         // A rows 0..127
    const size_t a1f = (size_t)(m0 + 128 + row_e) * K_DIM + ks_e;   // A rows 128..255
    const size_t b0f = (size_t)(n0 + row_e) * K_DIM + ks_e;         // B rows 0..127
    const int wA0 = tid * 8;            // u16 offset within a slot
    const int wA1 = 4096 + tid * 8;
    const int wB0 = tid * 8;

    f32x4 acc[4][4];
#pragma unroll
    for (int i = 0; i < 4; i++)
#pragma unroll
        for (int j = 0; j < 4; j++) acc[i][j] = (f32x4){0.f, 0.f, 0.f, 0.f};

    float4 g0[6], g1[6];

#define GLOAD(SET, kc) do {                                                  \
        const size_t k_ = (size_t)(kc) * 32;                                 \
        g##SET[0] = *(const float4*)(X + a0f + k_);                          \
        g##SET[1] = *(const float4*)(X + a0f + k_ + 4);                      \
        g##SET[2] = *(const float4*)(X + a1f + k_);                          \
        g##SET[3] = *(const float4*)(X + a1f + k_ + 4);                      \
        g##SET[4] = *(const float4*)(W + b0f + k_);                          \
        g##SET[5] = *(const float4*)(W + b0f + k_ + 4);                      \
    } while (0)

    // Dekker split of 8 f32 (two float4) -> uint4 hi + uint4 lo, element
    // order identical to the old split_bf16 kernel (bitwise-same LDS bytes).
#define DEK8(v0, v1, HI, LO) do {                                            \
        const float f_[8] = {v0.x, v0.y, v0.z, v0.w, v1.x, v1.y, v1.z, v1.w};\
        unsigned int hp_[4], lp_[4];                                         \
        _Pragma("unroll")                                                    \
        for (int q_ = 0; q_ < 8; q_ += 2) {                                  \
            u16 hh_[2], ll_[2];                                              \
            _Pragma("unroll")                                                \
            for (int e_ = 0; e_ < 2; e_++) {                                 \
                __hip_bfloat16 hb_ = __float2bfloat16(f_[q_ + e_]);          \
                const float hf_ = __bfloat162float(hb_);                     \
                __hip_bfloat16 lb_ = __float2bfloat16(f_[q_ + e_] - hf_);    \
                hh_[e_] = *(u16*)&hb_;                                       \
                ll_[e_] = *(u16*)&lb_;                                       \
            }                                                                \
            hp_[q_ >> 1] = (unsigned int)hh_[0] | ((unsigned int)hh_[1] << 16); \
            lp_[q_ >> 1] = (unsigned int)ll_[0] | ((unsigned int)ll_[1] << 16); \
        }                                                                    \
        HI = make_uint4(hp_[0], hp_[1], hp_[2], hp_[3]);                     \
        LO = make_uint4(lp_[0], lp_[1], lp_[2], lp_[3]);                     \
    } while (0)

#define CONVWRITE(s, SET) do {                                               \
        uint4 hA0_, lA0_, hA1_, lA1_, hB_, lB_;                              \
        DEK8(g##SET[0], g##SET[1], hA0_, lA0_);                              \
        DEK8(g##SET[2], g##SET[3], hA1_, lA1_);                              \
        DEK8(g##SET[4], g##SET[5], hB_, lB_);                                \
        *(uint4*)&sAh[(s) * 8192 + wA0] = hA0_;                              \
        *(uint4*)&sAl[(s) * 8192 + wA0] = lA0_;                              \
        *(uint4*)&sAh[(s) * 8192 + wA1] = hA1_;                              \
        *(uint4*)&sAl[(s) * 8192 + wA1] = lA1_;                              \
        *(uint4*)&sBh[(s) * 4096 + wB0] = hB_;                               \
        *(uint4*)&sBl[(s) * 4096 + wB0] = lB_;                               \
    } while (0)

#define COMPUTE(rs) do {                                                     \
        bf16x8 fah[4], fal[4], fbh[4], fbl[4];                               \
        _Pragma("unroll")                                                    \
        for (int ti = 0; ti < 4; ti++) {                                     \
            const int ta = wm * 4 + ti;                                      \
            fah[ti] = *(const bf16x8*)&sAh[(rs) * 8192 + (ta * 64 + lane) * 8]; \
            fal[ti] = *(const bf16x8*)&sAl[(rs) * 8192 + (ta * 64 + lane) * 8]; \
        }                                                                    \
        _Pragma("unroll")                                                    \
        for (int tj = 0; tj < 4; tj++) {                                     \
            const int tb = wn * 4 + tj;                                      \
            fbh[tj] = *(const bf16x8*)&sBh[(rs) * 4096 + (tb * 64 + lane) * 8]; \
            fbl[tj] = *(const bf16x8*)&sBl[(rs) * 4096 + (tb * 64 + lane) * 8]; \
        }                                                                    \
        __builtin_amdgcn_s_setprio(1);                                       \
        _Pragma("unroll")                                                    \
        for (int ti = 0; ti < 4; ti++)                                       \
        _Pragma("unroll")                                                    \
        for (int tj = 0; tj < 4; tj++) {                                     \
            acc[ti][tj] = __builtin_amdgcn_mfma_f32_16x16x32_bf16(           \
                fah[ti], fbh[tj], acc[ti][tj], 0, 0, 0);                     \
            acc[ti][tj] = __builtin_amdgcn_mfma_f32_16x16x32_bf16(           \
                fah[ti], fbl[tj], acc[ti][tj], 0, 0, 0);                     \
            acc[ti][tj] = __builtin_amdgcn_mfma_f32_16x16x32_bf16(           \
                fal[ti], fbh[tj], acc[ti][tj], 0, 0, 0);                     \
        }                                                                    \
        __builtin_amdgcn_s_setprio(0);                                       \
    } while (0)

#define BAR do {                                                             \
        __builtin_amdgcn_sched_barrier(0);                                   \
        __builtin_amdgcn_s_barrier();                                        \
        __builtin_amdgcn_sched_barrier(0);                                   \
    } while (0)
#define VMW(n) do {                                                          \
        asm volatile("s_waitcnt vmcnt(" #n ")" ::: "memory");                \
        __builtin_amdgcn_sched_barrier(0);                                   \
    } while (0)
#define LGKM0 do {                                                           \
        asm volatile("s_waitcnt lgkmcnt(0)" ::: "memory");                   \
        __builtin_amdgcn_sched_barrier(0);                                   \
    } while (0)

    // prologue: G(0) -> slot 0; G(1) in flight
    GLOAD(0, 0);
    VMW(0);
    CONVWRITE(0, 0);
    GLOAD(1, 1);
    LGKM0;

    // main loop: even/odd bodies, GLOADs reach kc+2 = 61
    for (int kc = 0; kc < 60; kc += 2) {
        // even body kc: read slot 0, write slot 1 from g1, load g0 <- kc+2
        BAR;
        GLOAD(0, kc + 2);
        VMW(6);
        CONVWRITE(1, 1);
        LGKM0;
        COMPUTE(0);
        // odd body kc+1: read slot 1, write slot 0 from g0, load g1 <- kc+3
        BAR;
        GLOAD(1, kc + 3);
        VMW(6);
        CONVWRITE(0, 0);
        LGKM0;
        COMPUTE(1);
    }
    // kc = 60 (even, full): GLOAD(0, 62)
    BAR;
    GLOAD(0, 62);
    VMW(6);
    CONVWRITE(1, 1);
    LGKM0;
    COMPUTE(0);
    // kc = 61 (odd, full): GLOAD(1, 63)
    BAR;
    GLOAD(1, 63);
    VMW(6);
    CONVWRITE(0, 0);
    LGKM0;
    COMPUTE(1);
    // kc = 62: no more loads; drain G(63), write slot 1 from g1
    BAR;
    VMW(0);
    CONVWRITE(1, 1);
    LGKM0;
    COMPUTE(0);
    // kc = 63: read slot 1 only
    BAR;
    COMPUTE(1);

#undef LGKM0
#undef VMW
#undef BAR
#undef COMPUTE
#undef CONVWRITE
#undef DEK8
#undef GLOAD

#pragma unroll
    for (int tj = 0; tj < 4; tj++) {
        const int n  = n0 + wn * 64 + tj * 16 + (lane & 15);
        const float bv = bias[n];
#pragma unroll
        for (int ti = 0; ti < 4; ti++) {
            const int mbase = m0 + wm * 64 + ti * 16 + (lane >> 4) * 4;
#pragma unroll
            for (int r = 0; r < 4; r++)
                C[(size_t)(mbase + r) * N_DIM + n] = acc[ti][tj][r] + bv;
        }
    }
}

// ---------------------------------------------------------------------------
// k4: banded scan, 4 chains/thread (float4 in/out). (R19, verbatim)
// ---------------------------------------------------------------------------
__global__ __launch_bounds__(256)
void lif_scan_band4(float* __restrict__ buf, unsigned int* __restrict__ counters,
                    unsigned int* __restrict__ worklist) {
    const int idx = (blockIdx.x * 256 + threadIdx.x) * 4;   // chain base
    float mem[4]  = {0.f, 0.f, 0.f, 0.f};
    bool  flag[4] = {false, false, false, false};
#pragma unroll
    for (int t = 0; t < T_STEPS; t++) {
        const size_t off = (size_t)t * NCHAIN + idx;
        const float4 v = *(const float4*)(buf + off);
        const float c[4] = {v.x, v.y, v.z, v.w};
        float s[4];
#pragma unroll
        for (int q = 0; q < 4; q++) {
            mem[q] = __fadd_rn(__fmul_rn(mem[q], DECAY_F32), c[q]);
            const float d = __fsub_rn(mem[q], 1.0f);
            const bool spk = d > 0.0f;
            if (fabsf(d) < BAND) flag[q] = true;
            s[q] = spk ? 1.0f : 0.0f;
            if (spk) mem[q] = __fsub_rn(mem[q], 1.0f);
        }
        *(float4*)(buf + off) = make_float4(s[0], s[1], s[2], s[3]);
    }
    const int b = idx >> 11;   // 4 consecutive chains share b (idx % 4 == 0)
#pragma unroll
    for (int q = 0; q < 4; q++) {
        if (flag[q]) {
            const unsigned int p = atomicAdd(&counters[b], 1u);
            worklist[b * 2048 + p] = (unsigned int)((idx + q) & 2047);
        }
    }
}

// ---------------------------------------------------------------------------
// k5: b-grouped exact repair (R16 coalesced X-staging). Unchanged.
// ---------------------------------------------------------------------------
#define RG 16    // chains per group
#define RJ 4     // block-strides per b
#define BKR 64   // k-chunk (320 = 5*64: panel boundaries land on chunk edges)

__global__ __launch_bounds__(256)
void lif_repair2(const float* __restrict__ X, const float* __restrict__ W,
                 const float* __restrict__ bias,
                 const unsigned int* __restrict__ counters,
                 const unsigned int* __restrict__ worklist,
                 float* __restrict__ out) {
    __shared__ float sX[BKR][T_STEPS + 1];      // [k][t] 16.25 KiB
    __shared__ float sW[RG][BKR + 1];           // [o][k]  4.06 KiB
    __shared__ float scur[T_STEPS][RG + 1];
    __shared__ float sspk[T_STEPS][RG + 1];
    __shared__ int   so[RG];

    const int b = blockIdx.x / RJ;
    const int j = blockIdx.x % RJ;
    const unsigned int n_b = counters[b];
    if (n_b == 0) return;
    const int ngroups = (int)(n_b + RG - 1) / RG;

    const int tid = threadIdx.x;
    const int t   = tid & 63;
    const int oi  = tid >> 6;          // 0..3, owns o-slots 4*oi .. 4*oi+3

    for (int g = j; g < ngroups; g += RJ) {
        if (tid < RG) {
            const int slot = g * RG + tid;
            so[tid] = (slot < (int)n_b) ? (int)worklist[b * 2048 + slot] : -1;
        }
        __syncthreads();

        float Csum[4] = {0.f, 0.f, 0.f, 0.f};
        float P[4]    = {0.f, 0.f, 0.f, 0.f};

        for (int c = 0; c < K_DIM / BKR; c++) {
            if (c > 0 && (c % 5) == 0) {       // k = 320*j panel boundary
#pragma unroll
                for (int q = 0; q < 4; q++) {
                    Csum[q] = __fadd_rn(Csum[q], P[q]);
                    P[q] = 0.f;
                }
            }
            const int k0 = c * BKR;
            // stage X chunk: 64 t x 64 k; lanes 4i..4i+3 read row i's 256 B
            {
                const int ts = tid >> 2;            // 0..63 row
                const int kq = (tid & 3) * 16;      // 0..48 col quarter
                const float* src = &X[(size_t)(ts * BATCH + b) * K_DIM + k0 + kq];
#pragma unroll
                for (int q = 0; q < 4; q++) {
                    const float4 v = *(const float4*)(src + q * 4);
                    sX[kq + q * 4 + 0][ts] = v.x;
                    sX[kq + q * 4 + 1][ts] = v.y;
                    sX[kq + q * 4 + 2][ts] = v.z;
                    sX[kq + q * 4 + 3][ts] = v.w;
                }
            }
            // stage W chunk: 16 o x 64 k, 1 float4 per thread
            {
                const int wo  = tid >> 4;          // 0..15
                const int wkq = (tid & 15) * 4;    // 0..60
                const int o   = so[wo];
                float4 v = {0.f, 0.f, 0.f, 0.f};
                if (o >= 0) v = *(const float4*)&W[(size_t)o * K_DIM + k0 + wkq];
                sW[wo][wkq + 0] = v.x; sW[wo][wkq + 1] = v.y;
                sW[wo][wkq + 2] = v.z; sW[wo][wkq + 3] = v.w;
            }
            __syncthreads();
            // exact sequential-k FMA, 4 independent chains (ILP)
#pragma unroll 8
            for (int k = 0; k < BKR; k++) {
                const float xv = sX[k][t];
#pragma unroll
                for (int q = 0; q < 4; q++)
                    P[q] = fmaf(xv, sW[oi * 4 + q][k], P[q]);
            }
            __syncthreads();
        }
#pragma unroll
        for (int q = 0; q < 4; q++) {
            Csum[q] = __fadd_rn(Csum[q], P[q]);    // final 128-elem panel
            const int o = so[oi * 4 + q];
            scur[t][oi * 4 + q] = (o >= 0) ? __fadd_rn(Csum[q], bias[o]) : 0.f;
        }
        __syncthreads();
        if (tid < RG && so[tid] >= 0) {
            float mem = 0.0f;
            for (int tt = 0; tt < T_STEPS; tt++) {
                mem = __fadd_rn(__fmul_rn(mem, DECAY_F32), scur[tt][tid]);
                const float d = __fsub_rn(mem, 1.0f);
                const bool spk = d > 0.0f;
                sspk[tt][tid] = spk ? 1.0f : 0.0f;
                if (spk) mem = __fsub_rn(mem, 1.0f);
            }
        }
        __syncthreads();
#pragma unroll
        for (int q = 0; q < 4; q++) {
            const int o = so[oi * 4 + q];
            if (o >= 0)
                out[(size_t)t * NCHAIN + (size_t)b * N_DIM + o] = sspk[t][oi * 4 + q];
        }
        __syncthreads();
    }
}

// ---------------------------------------------------------------------------
// FALLBACK (R8, known-passing, ws-free).
// ---------------------------------------------------------------------------
__global__ __launch_bounds__(256)
void lif_openblas_q320(const float* __restrict__ X, const float* __restrict__ W,
                       const float* __restrict__ bias, float* __restrict__ out) {
    __shared__ float As[16][T_STEPS + 4];
    __shared__ float Ws[16][64 + 4];
    __shared__ float curbuf[T_STEPS][64 + 1];
    const int tid = threadIdx.x;
    const int o0 = blockIdx.x * 64, b0 = blockIdx.y;
    const int tm = (tid & 15) * 4, tn = (tid >> 4) * 4;
    float Csum[4][4], Pacc[4][4];
#pragma unroll
    for (int i = 0; i < 4; i++)
#pragma unroll
        for (int j = 0; j < 4; j++) { Csum[i][j] = 0.f; Pacc[i][j] = 0.f; }
    for (int c = 0; c < K_DIM / 16; c++) {
        if (c > 0 && (c % 20) == 0) {
#pragma unroll
            for (int i = 0; i < 4; i++)
#pragma unroll
                for (int j = 0; j < 4; j++) {
                    Csum[i][j] = __fadd_rn(Csum[i][j], Pacc[i][j]);
                    Pacc[i][j] = 0.f;
                }
        }
        const int k0 = c * 16;
        {
            const int t = tid >> 2, kq = (tid & 3) * 4;
            const float4 av = *(const float4*)&X[(size_t)(t * BATCH + b0) * K_DIM + k0 + kq];
            As[kq + 0][t] = av.x; As[kq + 1][t] = av.y;
            As[kq + 2][t] = av.z; As[kq + 3][t] = av.w;
            const float4 wv = *(const float4*)&W[(size_t)(o0 + t) * K_DIM + k0 + kq];
            Ws[kq + 0][t] = wv.x; Ws[kq + 1][t] = wv.y;
            Ws[kq + 2][t] = wv.z; Ws[kq + 3][t] = wv.w;
        }
        __syncthreads();
#pragma unroll
        for (int k = 0; k < 16; k++) {
            float a[4], w[4];
#pragma unroll
            for (int i = 0; i < 4; i++) a[i] = As[k][tm + i];
#pragma unroll
            for (int j = 0; j < 4; j++) w[j] = Ws[k][tn + j];
#pragma unroll
            for (int i = 0; i < 4; i++)
#pragma unroll
                for (int j = 0; j < 4; j++) Pacc[i][j] = fmaf(a[i], w[j], Pacc[i][j]);
        }
        __syncthreads();
    }
#pragma unroll
    for (int i = 0; i < 4; i++)
#pragma unroll
        for (int j = 0; j < 4; j++)
            curbuf[tm + i][tn + j] =
                __fadd_rn(__fadd_rn(Csum[i][j], Pacc[i][j]), bias[o0 + tn + j]);
    __syncthreads();
    if (tid < 64) {
        float mem = 0.0f;
#pragma unroll
        for (int t = 0; t < T_STEPS; t++) {
            mem = __fadd_rn(__fmul_rn(mem, DECAY_F32), curbuf[t][tid]);
            const float d = __fsub_rn(mem, 1.0f);
            const bool spk = d > 0.0f;
            out[(size_t)t * NCHAIN + (size_t)b0 * N_DIM + o0 + tid] = spk ? 1.0f : 0.0f;
            if (spk) mem = __fsub_rn(mem, 1.0f);
        }
    }
}

extern "C" void kernel_launch(void* const* d_in, const int* in_sizes, int n_in,
                              void* d_out, int out_size, void* d_ws, size_t ws_size,
                              hipStream_t stream) {
    const float* x = nullptr; const float* W = nullptr; const float* bias = nullptr;
    for (int i = 0; i < n_in; i++) {
        if      (in_sizes[i] == M_DIM * K_DIM) x    = (const float*)d_in[i];
        else if (in_sizes[i] == N_DIM * K_DIM) W    = (const float*)d_in[i];
        else if (in_sizes[i] == N_DIM)         bias = (const float*)d_in[i];
    }
    if (!x)    x    = (const float*)d_in[0];
    if (!W)    W    = (const float*)d_in[1];
    if (!bias) bias = (const float*)d_in[2];
    float* out = (float*)d_out;

    // workspace layout: counters + worklist only (split buffers gone)
    const size_t off_cnt = 0;                                   // 128 u32
    const size_t off_wl  = 512;                                 // 128*2048 u32
    const size_t need    = off_wl + (size_t)128 * 2048 * 4;     // ~1.05 MB

    if (ws_size < need) {
        dim3 grid(N_DIM / 64, BATCH);
        lif_openblas_q320<<<grid, 256, 0, stream>>>(x, W, bias, out);
        return;
    }

    char* ws = (char*)d_ws;
    unsigned int* counters = (unsigned int*)(ws + off_cnt);
    unsigned int* worklist = (unsigned int*)(ws + off_wl);

    dim3 ggrid(N_DIM / 128, M_DIM / 256);   // (16, 32)
    gemm_bf16x3f<<<ggrid, 512, 98304, stream>>>(x, W, bias, out, counters);
    lif_scan_band4<<<NCHAIN / 1024, 256, 0, stream>>>(out, counters, worklist);
    lif_repair2<<<128 * RJ, 256, 0, stream>>>(x, W, bias, counters, worklist, out);
}

// Round 11
// 432.647 us; speedup vs baseline: 1.4419x; 1.0262x over previous
//
#include <hip/hip_runtime.h>
#include <hip/hip_bf16.h>
#include <math.h>

// ---------------------------------------------------------------------------
// LIF layer, round 21: R20 pipeline (fused split+GEMM kept, untouched) +
// (1) scan at 2 chains/thread (float2, 512 blocks -> 2x TLP for the
// latency-bound serial t-loop), (2) repair with register-staged chunk
// double-buffering (T14: next chunk's global loads issue under current
// chunk's compute; same values -> bitwise-identical repair numerics).
//
// R20 post-mortem: fusion net WIN (wall 456.9->444.0). Tail accounting:
// wall - gemm = 208us vs modeled scan ~25 + repair ~40 -> this round
// tests whether the tail is kernel-addressable (prediction: wall 405-430)
// or harness-fixed (wall ~440 -> near addressable floor).
// ---------------------------------------------------------------------------

typedef unsigned short u16;
typedef __attribute__((ext_vector_type(8))) short bf16x8;
typedef __attribute__((ext_vector_type(4))) float f32x4;

constexpr int T_STEPS = 64;
constexpr int BATCH   = 128;
constexpr int K_DIM   = 2048;
constexpr int N_DIM   = 2048;
constexpr int M_DIM   = T_STEPS * BATCH;      // 8192
constexpr int NCHAIN  = BATCH * N_DIM;        // 262144

constexpr float DECAY_F32 = (float)0.6065306597126334;
constexpr float BAND      = 2e-4f;            // error tail ~6e-5, 3.3x margin

// ---------------------------------------------------------------------------
// k3: fused split+GEMM (R20, verbatim). bf16x3 (hh+hl+lh), 256x128 tile,
// 8 waves, BK=32, 2-slot LDS ring (96 KiB), XCD swizzle, counted vmcnt.
// Block 0 zeroes the 128 per-b worklist counters.
// ---------------------------------------------------------------------------
__global__ __launch_bounds__(512, 2)
void gemm_bf16x3f(const float* __restrict__ X, const float* __restrict__ W,
                  const float* __restrict__ bias, float* __restrict__ C,
                  unsigned int* __restrict__ counters) {
    extern __shared__ __align__(16) u16 smem[];
    u16* const sAh = smem;                          // [2][8192]
    u16* const sAl = smem + 2 * 8192;               // [2][8192]
    u16* const sBh = smem + 4 * 8192;               // [2][4096]
    u16* const sBl = smem + 4 * 8192 + 2 * 4096;    // [2][4096]

    const int tid  = threadIdx.x;
    const int orig = blockIdx.x + gridDim.x * blockIdx.y;   // 0..511
    if (orig == 0 && tid < 128) counters[tid] = 0u;

    // XCD-chunked swizzle (bijective: 512 % 8 == 0)
    const int wg   = (orig & 7) * 64 + (orig >> 3);
    const int m0   = (wg >> 4) * 256;
    const int n0   = (wg & 15) * 128;
    const int lane = tid & 63;
    const int wave = tid >> 6;     // 0..7
    const int wm   = wave >> 1;    // 0..3 (64-row slab)
    const int wn   = wave & 1;     // 0..1 (64-col slab)

    const int row_e = (tid >> 6) * 16 + (tid & 15);
    const int ks_e  = ((tid >> 4) & 3) * 8;
    const size_t a0f = (size_t)(m0 + row_e) * K_DIM + ks_e;
    const size_t a1f = (size_t)(m0 + 128 + row_e) * K_DIM + ks_e;
    const size_t b0f = (size_t)(n0 + row_e) * K_DIM + ks_e;
    const int wA0 = tid * 8;
    const int wA1 = 4096 + tid * 8;
    const int wB0 = tid * 8;

    f32x4 acc[4][4];
#pragma unroll
    for (int i = 0; i < 4; i++)
#pragma unroll
        for (int j = 0; j < 4; j++) acc[i][j] = (f32x4){0.f, 0.f, 0.f, 0.f};

    float4 g0[6], g1[6];

#define GLOAD(SET, kc) do {                                                  \
        const size_t k_ = (size_t)(kc) * 32;                                 \
        g##SET[0] = *(const float4*)(X + a0f + k_);                          \
        g##SET[1] = *(const float4*)(X + a0f + k_ + 4);                      \
        g##SET[2] = *(const float4*)(X + a1f + k_);                          \
        g##SET[3] = *(const float4*)(X + a1f + k_ + 4);                      \
        g##SET[4] = *(const float4*)(W + b0f + k_);                          \
        g##SET[5] = *(const float4*)(W + b0f + k_ + 4);                      \
    } while (0)

#define DEK8(v0, v1, HI, LO) do {                                            \
        const float f_[8] = {v0.x, v0.y, v0.z, v0.w, v1.x, v1.y, v1.z, v1.w};\
        unsigned int hp_[4], lp_[4];                                         \
        _Pragma("unroll")                                                    \
        for (int q_ = 0; q_ < 8; q_ += 2) {                                  \
            u16 hh_[2], ll_[2];                                              \
            _Pragma("unroll")                                                \
            for (int e_ = 0; e_ < 2; e_++) {                                 \
                __hip_bfloat16 hb_ = __float2bfloat16(f_[q_ + e_]);          \
                const float hf_ = __bfloat162float(hb_);                     \
                __hip_bfloat16 lb_ = __float2bfloat16(f_[q_ + e_] - hf_);    \
                hh_[e_] = *(u16*)&hb_;                                       \
                ll_[e_] = *(u16*)&lb_;                                       \
            }                                                                \
            hp_[q_ >> 1] = (unsigned int)hh_[0] | ((unsigned int)hh_[1] << 16); \
            lp_[q_ >> 1] = (unsigned int)ll_[0] | ((unsigned int)ll_[1] << 16); \
        }                                                                    \
        HI = make_uint4(hp_[0], hp_[1], hp_[2], hp_[3]);                     \
        LO = make_uint4(lp_[0], lp_[1], lp_[2], lp_[3]);                     \
    } while (0)

#define CONVWRITE(s, SET) do {                                               \
        uint4 hA0_, lA0_, hA1_, lA1_, hB_, lB_;                              \
        DEK8(g##SET[0], g##SET[1], hA0_, lA0_);                              \
        DEK8(g##SET[2], g##SET[3], hA1_, lA1_);                              \
        DEK8(g##SET[4], g##SET[5], hB_, lB_);                                \
        *(uint4*)&sAh[(s) * 8192 + wA0] = hA0_;                              \
        *(uint4*)&sAl[(s) * 8192 + wA0] = lA0_;                              \
        *(uint4*)&sAh[(s) * 8192 + wA1] = hA1_;                              \
        *(uint4*)&sAl[(s) * 8192 + wA1] = lA1_;                              \
        *(uint4*)&sBh[(s) * 4096 + wB0] = hB_;                               \
        *(uint4*)&sBl[(s) * 4096 + wB0] = lB_;                               \
    } while (0)

#define COMPUTE(rs) do {                                                     \
        bf16x8 fah[4], fal[4], fbh[4], fbl[4];                               \
        _Pragma("unroll")                                                    \
        for (int ti = 0; ti < 4; ti++) {                                     \
            const int ta = wm * 4 + ti;                                      \
            fah[ti] = *(const bf16x8*)&sAh[(rs) * 8192 + (ta * 64 + lane) * 8]; \
            fal[ti] = *(const bf16x8*)&sAl[(rs) * 8192 + (ta * 64 + lane) * 8]; \
        }                                                                    \
        _Pragma("unroll")                                                    \
        for (int tj = 0; tj < 4; tj++) {                                     \
            const int tb = wn * 4 + tj;                                      \
            fbh[tj] = *(const bf16x8*)&sBh[(rs) * 4096 + (tb * 64 + lane) * 8]; \
            fbl[tj] = *(const bf16x8*)&sBl[(rs) * 4096 + (tb * 64 + lane) * 8]; \
        }                                                                    \
        __builtin_amdgcn_s_setprio(1);                                       \
        _Pragma("unroll")                                                    \
        for (int ti = 0; ti < 4; ti++)                                       \
        _Pragma("unroll")                                                    \
        for (int tj = 0; tj < 4; tj++) {                                     \
            acc[ti][tj] = __builtin_amdgcn_mfma_f32_16x16x32_bf16(           \
                fah[ti], fbh[tj], acc[ti][tj], 0, 0, 0);                     \
            acc[ti][tj] = __builtin_amdgcn_mfma_f32_16x16x32_bf16(           \
                fah[ti], fbl[tj], acc[ti][tj], 0, 0, 0);                     \
            acc[ti][tj] = __builtin_amdgcn_mfma_f32_16x16x32_bf16(           \
                fal[ti], fbh[tj], acc[ti][tj], 0, 0, 0);                     \
        }                                                                    \
        __builtin_amdgcn_s_setprio(0);                                       \
    } while (0)

#define BAR do {                                                             \
        __builtin_amdgcn_sched_barrier(0);                                   \
        __builtin_amdgcn_s_barrier();                                        \
        __builtin_amdgcn_sched_barrier(0);                                   \
    } while (0)
#define VMW(n) do {                                                          \
        asm volatile("s_waitcnt vmcnt(" #n ")" ::: "memory");                \
        __builtin_amdgcn_sched_barrier(0);                                   \
    } while (0)
#define LGKM0 do {                                                           \
        asm volatile("s_waitcnt lgkmcnt(0)" ::: "memory");                   \
        __builtin_amdgcn_sched_barrier(0);                                   \
    } while (0)

    // prologue: G(0) -> slot 0; G(1) in flight
    GLOAD(0, 0);
    VMW(0);
    CONVWRITE(0, 0);
    GLOAD(1, 1);
    LGKM0;

    for (int kc = 0; kc < 60; kc += 2) {
        BAR;
        GLOAD(0, kc + 2);
        VMW(6);
        CONVWRITE(1, 1);
        LGKM0;
        COMPUTE(0);
        BAR;
        GLOAD(1, kc + 3);
        VMW(6);
        CONVWRITE(0, 0);
        LGKM0;
        COMPUTE(1);
    }
    BAR;
    GLOAD(0, 62);
    VMW(6);
    CONVWRITE(1, 1);
    LGKM0;
    COMPUTE(0);
    BAR;
    GLOAD(1, 63);
    VMW(6);
    CONVWRITE(0, 0);
    LGKM0;
    COMPUTE(1);
    BAR;
    VMW(0);
    CONVWRITE(1, 1);
    LGKM0;
    COMPUTE(0);
    BAR;
    COMPUTE(1);

#undef LGKM0
#undef VMW
#undef BAR
#undef COMPUTE
#undef CONVWRITE
#undef DEK8
#undef GLOAD

#pragma unroll
    for (int tj = 0; tj < 4; tj++) {
        const int n  = n0 + wn * 64 + tj * 16 + (lane & 15);
        const float bv = bias[n];
#pragma unroll
        for (int ti = 0; ti < 4; ti++) {
            const int mbase = m0 + wm * 64 + ti * 16 + (lane >> 4) * 4;
#pragma unroll
            for (int r = 0; r < 4; r++)
                C[(size_t)(mbase + r) * N_DIM + n] = acc[ti][tj][r] + bv;
        }
    }
}

// ---------------------------------------------------------------------------
// k4: banded scan, 2 chains/thread (float2 in/out, 512 blocks -> 2x TLP).
// Per-chain numerics identical to scalar/float4 versions.
// ---------------------------------------------------------------------------
__global__ __launch_bounds__(256)
void lif_scan_band2(float* __restrict__ buf, unsigned int* __restrict__ counters,
                    unsigned int* __restrict__ worklist) {
    const int idx = (blockIdx.x * 256 + threadIdx.x) * 2;   // chain base
    float mem[2]  = {0.f, 0.f};
    bool  flag[2] = {false, false};
#pragma unroll
    for (int t = 0; t < T_STEPS; t++) {
        const size_t off = (size_t)t * NCHAIN + idx;
        const float2 v = *(const float2*)(buf + off);
        const float c[2] = {v.x, v.y};
        float s[2];
#pragma unroll
        for (int q = 0; q < 2; q++) {
            mem[q] = __fadd_rn(__fmul_rn(mem[q], DECAY_F32), c[q]);
            const float d = __fsub_rn(mem[q], 1.0f);
            const bool spk = d > 0.0f;
            if (fabsf(d) < BAND) flag[q] = true;
            s[q] = spk ? 1.0f : 0.0f;
            if (spk) mem[q] = __fsub_rn(mem[q], 1.0f);
        }
        *(float2*)(buf + off) = make_float2(s[0], s[1]);
    }
    const int b = idx >> 11;   // both chains share b (idx even)
#pragma unroll
    for (int q = 0; q < 2; q++) {
        if (flag[q]) {
            const unsigned int p = atomicAdd(&counters[b], 1u);
            worklist[b * 2048 + p] = (unsigned int)((idx + q) & 2047);
        }
    }
}

// ---------------------------------------------------------------------------
// k5: b-grouped exact repair + register-staged chunk double-buffer (T14):
// chunk c+1's global loads issue under chunk c's compute; LDS contents and
// summation order bitwise identical to R20 -> repair numerics unchanged.
// ---------------------------------------------------------------------------
#define RG 16    // chains per group
#define RJ 4     // block-strides per b
#define BKR 64   // k-chunk (320 = 5*64: panel boundaries land on chunk edges)

__global__ __launch_bounds__(256)
void lif_repair2(const float* __restrict__ X, const float* __restrict__ W,
                 const float* __restrict__ bias,
                 const unsigned int* __restrict__ counters,
                 const unsigned int* __restrict__ worklist,
                 float* __restrict__ out) {
    __shared__ float sX[BKR][T_STEPS + 1];      // [k][t] 16.25 KiB
    __shared__ float sW[RG][BKR + 1];           // [o][k]  4.06 KiB
    __shared__ float scur[T_STEPS][RG + 1];
    __shared__ float sspk[T_STEPS][RG + 1];
    __shared__ int   so[RG];

    const int b = blockIdx.x / RJ;
    const int j = blockIdx.x % RJ;
    const unsigned int n_b = counters[b];
    if (n_b == 0) return;
    const int ngroups = (int)(n_b + RG - 1) / RG;

    const int tid = threadIdx.x;
    const int t   = tid & 63;
    const int oi  = tid >> 6;          // 0..3, owns o-slots 4*oi .. 4*oi+3

    // staging roles (constant per thread)
    const int ts  = tid >> 2;          // X row 0..63
    const int kq  = (tid & 3) * 16;    // X col quarter
    const int wo  = tid >> 4;          // W row 0..15
    const int wkq = (tid & 15) * 4;    // W col quad

    for (int g = j; g < ngroups; g += RJ) {
        if (tid < RG) {
            const int slot = g * RG + tid;
            so[tid] = (slot < (int)n_b) ? (int)worklist[b * 2048 + slot] : -1;
        }
        __syncthreads();

        float Csum[4] = {0.f, 0.f, 0.f, 0.f};
        float P[4]    = {0.f, 0.f, 0.f, 0.f};

        // preload chunk 0 into registers
        float4 rx[4];
        float4 rw;
        {
            const float* srcx = &X[(size_t)(ts * BATCH + b) * K_DIM + kq];
#pragma unroll
            for (int q = 0; q < 4; q++) rx[q] = *(const float4*)(srcx + q * 4);
            const int o = so[wo];
            rw = (o >= 0) ? *(const float4*)&W[(size_t)o * K_DIM + wkq]
                          : make_float4(0.f, 0.f, 0.f, 0.f);
        }

        for (int c = 0; c < K_DIM / BKR; c++) {
            if (c > 0 && (c % 5) == 0) {       // k = 320*j panel boundary
#pragma unroll
                for (int q = 0; q < 4; q++) {
                    Csum[q] = __fadd_rn(Csum[q], P[q]);
                    P[q] = 0.f;
                }
            }
            __syncthreads();                   // prev chunk's LDS reads done
            // write staged registers to LDS (same values/layout as R20)
#pragma unroll
            for (int q = 0; q < 4; q++) {
                sX[kq + q * 4 + 0][ts] = rx[q].x;
                sX[kq + q * 4 + 1][ts] = rx[q].y;
                sX[kq + q * 4 + 2][ts] = rx[q].z;
                sX[kq + q * 4 + 3][ts] = rx[q].w;
            }
            sW[wo][wkq + 0] = rw.x; sW[wo][wkq + 1] = rw.y;
            sW[wo][wkq + 2] = rw.z; sW[wo][wkq + 3] = rw.w;
            // issue next chunk's global loads (hide under compute below)
            if (c + 1 < K_DIM / BKR) {
                const int k1 = (c + 1) * BKR;
                const float* srcx = &X[(size_t)(ts * BATCH + b) * K_DIM + k1 + kq];
#pragma unroll
                for (int q = 0; q < 4; q++) rx[q] = *(const float4*)(srcx + q * 4);
                const int o = so[wo];
                rw = (o >= 0) ? *(const float4*)&W[(size_t)o * K_DIM + k1 + wkq]
                              : make_float4(0.f, 0.f, 0.f, 0.f);
            }
            __syncthreads();                   // LDS chunk c ready
            // exact sequential-k FMA, 4 independent chains (ILP)
#pragma unroll 8
            for (int k = 0; k < BKR; k++) {
                const float xv = sX[k][t];
#pragma unroll
                for (int q = 0; q < 4; q++)
                    P[q] = fmaf(xv, sW[oi * 4 + q][k], P[q]);
            }
        }
        __syncthreads();
#pragma unroll
        for (int q = 0; q < 4; q++) {
            Csum[q] = __fadd_rn(Csum[q], P[q]);    // final 128-elem panel
            const int o = so[oi * 4 + q];
            scur[t][oi * 4 + q] = (o >= 0) ? __fadd_rn(Csum[q], bias[o]) : 0.f;
        }
        __syncthreads();
        if (tid < RG && so[tid] >= 0) {
            float mem = 0.0f;
            for (int tt = 0; tt < T_STEPS; tt++) {
                mem = __fadd_rn(__fmul_rn(mem, DECAY_F32), scur[tt][tid]);
                const float d = __fsub_rn(mem, 1.0f);
                const bool spk = d > 0.0f;
                sspk[tt][tid] = spk ? 1.0f : 0.0f;
                if (spk) mem = __fsub_rn(mem, 1.0f);
            }
        }
        __syncthreads();
#pragma unroll
        for (int q = 0; q < 4; q++) {
            const int o = so[oi * 4 + q];
            if (o >= 0)
                out[(size_t)t * NCHAIN + (size_t)b * N_DIM + o] = sspk[t][oi * 4 + q];
        }
        __syncthreads();
    }
}

// ---------------------------------------------------------------------------
// FALLBACK (R8, known-passing, ws-free).
// ---------------------------------------------------------------------------
__global__ __launch_bounds__(256)
void lif_openblas_q320(const float* __restrict__ X, const float* __restrict__ W,
                       const float* __restrict__ bias, float* __restrict__ out) {
    __shared__ float As[16][T_STEPS + 4];
    __shared__ float Ws[16][64 + 4];
    __shared__ float curbuf[T_STEPS][64 + 1];
    const int tid = threadIdx.x;
    const int o0 = blockIdx.x * 64, b0 = blockIdx.y;
    const int tm = (tid & 15) * 4, tn = (tid >> 4) * 4;
    float Csum[4][4], Pacc[4][4];
#pragma unroll
    for (int i = 0; i < 4; i++)
#pragma unroll
        for (int j = 0; j < 4; j++) { Csum[i][j] = 0.f; Pacc[i][j] = 0.f; }
    for (int c = 0; c < K_DIM / 16; c++) {
        if (c > 0 && (c % 20) == 0) {
#pragma unroll
            for (int i = 0; i < 4; i++)
#pragma unroll
                for (int j = 0; j < 4; j++) {
                    Csum[i][j] = __fadd_rn(Csum[i][j], Pacc[i][j]);
                    Pacc[i][j] = 0.f;
                }
        }
        const int k0 = c * 16;
        {
            const int t = tid >> 2, kq = (tid & 3) * 4;
            const float4 av = *(const float4*)&X[(size_t)(t * BATCH + b0) * K_DIM + k0 + kq];
            As[kq + 0][t] = av.x; As[kq + 1][t] = av.y;
            As[kq + 2][t] = av.z; As[kq + 3][t] = av.w;
            const float4 wv = *(const float4*)&W[(size_t)(o0 + t) * K_DIM + k0 + kq];
            Ws[kq + 0][t] = wv.x; Ws[kq + 1][t] = wv.y;
            Ws[kq + 2][t] = wv.z; Ws[kq + 3][t] = wv.w;
        }
        __syncthreads();
#pragma unroll
        for (int k = 0; k < 16; k++) {
            float a[4], w[4];
#pragma unroll
            for (int i = 0; i < 4; i++) a[i] = As[k][tm + i];
#pragma unroll
            for (int j = 0; j < 4; j++) w[j] = Ws[k][tn + j];
#pragma unroll
            for (int i = 0; i < 4; i++)
#pragma unroll
                for (int j = 0; j < 4; j++) Pacc[i][j] = fmaf(a[i], w[j], Pacc[i][j]);
        }
        __syncthreads();
    }
#pragma unroll
    for (int i = 0; i < 4; i++)
#pragma unroll
        for (int j = 0; j < 4; j++)
            curbuf[tm + i][tn + j] =
                __fadd_rn(__fadd_rn(Csum[i][j], Pacc[i][j]), bias[o0 + tn + j]);
    __syncthreads();
    if (tid < 64) {
        float mem = 0.0f;
#pragma unroll
        for (int t = 0; t < T_STEPS; t++) {
            mem = __fadd_rn(__fmul_rn(mem, DECAY_F32), curbuf[t][tid]);
            const float d = __fsub_rn(mem, 1.0f);
            const bool spk = d > 0.0f;
            out[(size_t)t * NCHAIN + (size_t)b0 * N_DIM + o0 + tid] = spk ? 1.0f : 0.0f;
            if (spk) mem = __fsub_rn(mem, 1.0f);
        }
    }
}

extern "C" void kernel_launch(void* const* d_in, const int* in_sizes, int n_in,
                              void* d_out, int out_size, void* d_ws, size_t ws_size,
                              hipStream_t stream) {
    const float* x = nullptr; const float* W = nullptr; const float* bias = nullptr;
    for (int i = 0; i < n_in; i++) {
        if      (in_sizes[i] == M_DIM * K_DIM) x    = (const float*)d_in[i];
        else if (in_sizes[i] == N_DIM * K_DIM) W    = (const float*)d_in[i];
        else if (in_sizes[i] == N_DIM)         bias = (const float*)d_in[i];
    }
    if (!x)    x    = (const float*)d_in[0];
    if (!W)    W    = (const float*)d_in[1];
    if (!bias) bias = (const float*)d_in[2];
    float* out = (float*)d_out;

    // workspace layout: counters + worklist only
    const size_t off_cnt = 0;                                   // 128 u32
    const size_t off_wl  = 512;                                 // 128*2048 u32
    const size_t need    = off_wl + (size_t)128 * 2048 * 4;     // ~1.05 MB

    if (ws_size < need) {
        dim3 grid(N_DIM / 64, BATCH);
        lif_openblas_q320<<<grid, 256, 0, stream>>>(x, W, bias, out);
        return;
    }

    char* ws = (char*)d_ws;
    unsigned int* counters = (unsigned int*)(ws + off_cnt);
    unsigned int* worklist = (unsigned int*)(ws + off_wl);

    dim3 ggrid(N_DIM / 128, M_DIM / 256);   // (16, 32)
    gemm_bf16x3f<<<ggrid, 512, 98304, stream>>>(x, W, bias, out, counters);
    lif_scan_band2<<<NCHAIN / 512, 256, 0, stream>>>(out, counters, worklist);
    lif_repair2<<<128 * RJ, 256, 0, stream>>>(x, W, bias, counters, worklist, out);
}

// Round 12
// 418.498 us; speedup vs baseline: 1.4906x; 1.0338x over previous
//
#include <hip/hip_runtime.h>
#include <hip/hip_bf16.h>
#include <math.h>

// ---------------------------------------------------------------------------
// LIF layer, round 22: SCAN KERNEL DELETED — M retiled so each GEMM block
// owns complete t-chains (M-tile = 64 t x 4 b), LIF scan runs in-LDS in the
// GEMM epilogue, spikes written directly, flagged chains -> worklist.
//
// R21 post-mortem: wall 444->432.6; gemm flat at 236 (plateau after 6
// structured attacks). Tail ~197us; biggest deletable item = scan's 128MB
// round-trip + launch. Row-permutation of the M-tile is free: staging loads
// were already 16 lanes x 32B at 8KB stride (per-row scatter), and MFMA is
// row-permutation-invariant. Epilogue: acc+bias -> LDS cur[256][129] (pad
// avoids 4-way store conflict), barrier, 1 chain/thread scan (identical f32
// ops -> identical spikes/band flags -> absmax 0.0). Counters zeroed via
// hipMemsetAsync before the gemm (worklist atomics now happen in-gemm).
//
// Pipeline: memset(counters) / k3 gemm+scan / k5 repair. Fallback: R8.
// ---------------------------------------------------------------------------

typedef unsigned short u16;
typedef __attribute__((ext_vector_type(8))) short bf16x8;
typedef __attribute__((ext_vector_type(4))) float f32x4;

constexpr int T_STEPS = 64;
constexpr int BATCH   = 128;
constexpr int K_DIM   = 2048;
constexpr int N_DIM   = 2048;
constexpr int M_DIM   = T_STEPS * BATCH;      // 8192
constexpr int NCHAIN  = BATCH * N_DIM;        // 262144

constexpr float DECAY_F32 = (float)0.6065306597126334;
constexpr float BAND      = 2e-4f;            // error tail ~6e-5, 3.3x margin

// ---------------------------------------------------------------------------
// k3: fused split+GEMM+scan. bf16x3 (hh+hl+lh), tile = (64t x 4b) x 128o,
// 8 waves, BK=32, 2-slot LDS ring (96 KiB), XCD swizzle, counted vmcnt.
// Epilogue: in-LDS LIF scan, spikes -> out, flagged chains -> worklist.
// ---------------------------------------------------------------------------
__global__ __launch_bounds__(512, 2)
void gemm_lif(const float* __restrict__ X, const float* __restrict__ W,
              const float* __restrict__ bias, float* __restrict__ out,
              unsigned int* __restrict__ counters,
              unsigned int* __restrict__ worklist) {
    extern __shared__ __align__(16) u16 smem[];
    u16* const sAh = smem;                          // [2][8192]
    u16* const sAl = smem + 2 * 8192;               // [2][8192]
    u16* const sBh = smem + 4 * 8192;               // [2][4096]
    u16* const sBl = smem + 4 * 8192 + 2 * 4096;    // [2][4096]

    const int tid  = threadIdx.x;
    const int orig = blockIdx.x + gridDim.x * blockIdx.y;   // 0..511
    // XCD-chunked swizzle (bijective: 512 % 8 == 0)
    const int wg   = (orig & 7) * 64 + (orig >> 3);
    const int b0i  = (wg >> 4) * 4;     // batch base (4 b per tile)
    const int n0   = (wg & 15) * 128;   // output-channel base
    const int lane = tid & 63;
    const int wave = tid >> 6;     // 0..7
    const int wm   = wave >> 1;    // 0..3 (64-row slab)
    const int wn   = wave & 1;     // 0..1 (64-col slab)

    // staging entry: tile row re = (tid>>6)*16 + (tid&15), k-slot ((tid>>4)&3)*8
    // tile row r <-> global A row (r>>2)*128 + b0i + (r&3)   [t = r>>2, bl = r&3]
    const int re   = (tid >> 6) * 16 + (tid & 15);   // 0..127
    const int ks_e = ((tid >> 4) & 3) * 8;
    const size_t a0f = (size_t)((re >> 2) * 128 + b0i + (re & 3)) * K_DIM + ks_e;
    const size_t a1f = (size_t)(((re >> 2) + 32) * 128 + b0i + (re & 3)) * K_DIM + ks_e;
    const size_t b0f = (size_t)(n0 + re) * K_DIM + ks_e;
    const int wA0 = tid * 8;            // u16 offset within a slot
    const int wA1 = 4096 + tid * 8;
    const int wB0 = tid * 8;

    f32x4 acc[4][4];
#pragma unroll
    for (int i = 0; i < 4; i++)
#pragma unroll
        for (int j = 0; j < 4; j++) acc[i][j] = (f32x4){0.f, 0.f, 0.f, 0.f};

    float4 g0[6], g1[6];

#define GLOAD(SET, kc) do {                                                  \
        const size_t k_ = (size_t)(kc) * 32;                                 \
        g##SET[0] = *(const float4*)(X + a0f + k_);                          \
        g##SET[1] = *(const float4*)(X + a0f + k_ + 4);                      \
        g##SET[2] = *(const float4*)(X + a1f + k_);                          \
        g##SET[3] = *(const float4*)(X + a1f + k_ + 4);                      \
        g##SET[4] = *(const float4*)(W + b0f + k_);                          \
        g##SET[5] = *(const float4*)(W + b0f + k_ + 4);                      \
    } while (0)

#define DEK8(v0, v1, HI, LO) do {                                            \
        const float f_[8] = {v0.x, v0.y, v0.z, v0.w, v1.x, v1.y, v1.z, v1.w};\
        unsigned int hp_[4], lp_[4];                                         \
        _Pragma("unroll")                                                    \
        for (int q_ = 0; q_ < 8; q_ += 2) {                                  \
            u16 hh_[2], ll_[2];                                              \
            _Pragma("unroll")                                                \
            for (int e_ = 0; e_ < 2; e_++) {                                 \
                __hip_bfloat16 hb_ = __float2bfloat16(f_[q_ + e_]);          \
                const float hf_ = __bfloat162float(hb_);                     \
                __hip_bfloat16 lb_ = __float2bfloat16(f_[q_ + e_] - hf_);    \
                hh_[e_] = *(u16*)&hb_;                                       \
                ll_[e_] = *(u16*)&lb_;                                       \
            }                                                                \
            hp_[q_ >> 1] = (unsigned int)hh_[0] | ((unsigned int)hh_[1] << 16); \
            lp_[q_ >> 1] = (unsigned int)ll_[0] | ((unsigned int)ll_[1] << 16); \
        }                                                                    \
        HI = make_uint4(hp_[0], hp_[1], hp_[2], hp_[3]);                     \
        LO = make_uint4(lp_[0], lp_[1], lp_[2], lp_[3]);                     \
    } while (0)

#define CONVWRITE(s, SET) do {                                               \
        uint4 hA0_, lA0_, hA1_, lA1_, hB_, lB_;                              \
        DEK8(g##SET[0], g##SET[1], hA0_, lA0_);                              \
        DEK8(g##SET[2], g##SET[3], hA1_, lA1_);                              \
        DEK8(g##SET[4], g##SET[5], hB_, lB_);                                \
        *(uint4*)&sAh[(s) * 8192 + wA0] = hA0_;                              \
        *(uint4*)&sAl[(s) * 8192 + wA0] = lA0_;                              \
        *(uint4*)&sAh[(s) * 8192 + wA1] = hA1_;                              \
        *(uint4*)&sAl[(s) * 8192 + wA1] = lA1_;                              \
        *(uint4*)&sBh[(s) * 4096 + wB0] = hB_;                               \
        *(uint4*)&sBl[(s) * 4096 + wB0] = lB_;                               \
    } while (0)

#define COMPUTE(rs) do {                                                     \
        bf16x8 fah[4], fal[4], fbh[4], fbl[4];                               \
        _Pragma("unroll")                                                    \
        for (int ti = 0; ti < 4; ti++) {                                     \
            const int ta = wm * 4 + ti;                                      \
            fah[ti] = *(const bf16x8*)&sAh[(rs) * 8192 + (ta * 64 + lane) * 8]; \
            fal[ti] = *(const bf16x8*)&sAl[(rs) * 8192 + (ta * 64 + lane) * 8]; \
        }                                                                    \
        _Pragma("unroll")                                                    \
        for (int tj = 0; tj < 4; tj++) {                                     \
            const int tb = wn * 4 + tj;                                      \
            fbh[tj] = *(const bf16x8*)&sBh[(rs) * 4096 + (tb * 64 + lane) * 8]; \
            fbl[tj] = *(const bf16x8*)&sBl[(rs) * 4096 + (tb * 64 + lane) * 8]; \
        }                                                                    \
        __builtin_amdgcn_s_setprio(1);                                       \
        _Pragma("unroll")                                                    \
        for (int ti = 0; ti < 4; ti++)                                       \
        _Pragma("unroll")                                                    \
        for (int tj = 0; tj < 4; tj++) {                                     \
            acc[ti][tj] = __builtin_amdgcn_mfma_f32_16x16x32_bf16(           \
                fah[ti], fbh[tj], acc[ti][tj], 0, 0, 0);                     \
            acc[ti][tj] = __builtin_amdgcn_mfma_f32_16x16x32_bf16(           \
                fah[ti], fbl[tj], acc[ti][tj], 0, 0, 0);                     \
            acc[ti][tj] = __builtin_amdgcn_mfma_f32_16x16x32_bf16(           \
                fal[ti], fbh[tj], acc[ti][tj], 0, 0, 0);                     \
        }                                                                    \
        __builtin_amdgcn_s_setprio(0);                                       \
    } while (0)

#define BAR do {                                                             \
        __builtin_amdgcn_sched_barrier(0);                                   \
        __builtin_amdgcn_s_barrier();                                        \
        __builtin_amdgcn_sched_barrier(0);                                   \
    } while (0)
#define VMW(n) do {                                                          \
        asm volatile("s_waitcnt vmcnt(" #n ")" ::: "memory");                \
        __builtin_amdgcn_sched_barrier(0);                                   \
    } while (0)
#define LGKM0 do {                                                           \
        asm volatile("s_waitcnt lgkmcnt(0)" ::: "memory");                   \
        __builtin_amdgcn_sched_barrier(0);                                   \
    } while (0)

    // prologue: G(0) -> slot 0; G(1) in flight
    GLOAD(0, 0);
    VMW(0);
    CONVWRITE(0, 0);
    GLOAD(1, 1);
    LGKM0;

    for (int kc = 0; kc < 60; kc += 2) {
        BAR;
        GLOAD(0, kc + 2);
        VMW(6);
        CONVWRITE(1, 1);
        LGKM0;
        COMPUTE(0);
        BAR;
        GLOAD(1, kc + 3);
        VMW(6);
        CONVWRITE(0, 0);
        LGKM0;
        COMPUTE(1);
    }
    BAR;
    GLOAD(0, 62);
    VMW(6);
    CONVWRITE(1, 1);
    LGKM0;
    COMPUTE(0);
    BAR;
    GLOAD(1, 63);
    VMW(6);
    CONVWRITE(0, 0);
    LGKM0;
    COMPUTE(1);
    BAR;
    VMW(0);
    CONVWRITE(1, 1);
    LGKM0;
    COMPUTE(0);
    BAR;
    COMPUTE(1);

#undef LGKM0
#undef VMW
#undef BAR
#undef COMPUTE
#undef CONVWRITE
#undef DEK8
#undef GLOAD

    // ------------------------------------------------------------------
    // epilogue: reuse smem as cur[256][129] f32 (132096 B), in-LDS scan.
    // ------------------------------------------------------------------
    __syncthreads();                    // all ring reads done, smem reusable
    float* const curL = (float*)smem;

#pragma unroll
    for (int tj = 0; tj < 4; tj++) {
        const int col = wn * 64 + tj * 16 + (lane & 15);
        const float bv = bias[n0 + col];
#pragma unroll
        for (int ti = 0; ti < 4; ti++) {
            const int rb = wm * 64 + ti * 16 + (lane >> 4) * 4;
#pragma unroll
            for (int r = 0; r < 4; r++)
                curL[(rb + r) * 129 + col] = acc[ti][tj][r] + bv;
        }
    }
    __syncthreads();                    // cur tile complete

    // scan: 512 threads = 512 chains (bl = tid>>7, col = tid&127)
    {
        const int bl  = tid >> 7;
        const int col = tid & 127;
        const int b   = b0i + bl;
        const int o   = n0 + col;
        float mem = 0.0f;
        bool flag = false;
#pragma unroll
        for (int t = 0; t < T_STEPS; t++) {
            const float cv = curL[(t * 4 + bl) * 129 + col];
            mem = __fadd_rn(__fmul_rn(mem, DECAY_F32), cv);
            const float d = __fsub_rn(mem, 1.0f);
            const bool spk = d > 0.0f;
            if (fabsf(d) < BAND) flag = true;
            out[(size_t)t * NCHAIN + (size_t)b * N_DIM + o] = spk ? 1.0f : 0.0f;
            if (spk) mem = __fsub_rn(mem, 1.0f);
        }
        if (flag) {
            const unsigned int p = atomicAdd(&counters[b], 1u);
            worklist[b * 2048 + p] = (unsigned int)o;
        }
    }
}

// ---------------------------------------------------------------------------
// k5: b-grouped exact repair + register-staged chunk double-buffer (R21).
// ---------------------------------------------------------------------------
#define RG 16    // chains per group
#define RJ 4     // block-strides per b
#define BKR 64   // k-chunk (320 = 5*64: panel boundaries land on chunk edges)

__global__ __launch_bounds__(256)
void lif_repair2(const float* __restrict__ X, const float* __restrict__ W,
                 const float* __restrict__ bias,
                 const unsigned int* __restrict__ counters,
                 const unsigned int* __restrict__ worklist,
                 float* __restrict__ out) {
    __shared__ float sX[BKR][T_STEPS + 1];      // [k][t] 16.25 KiB
    __shared__ float sW[RG][BKR + 1];           // [o][k]  4.06 KiB
    __shared__ float scur[T_STEPS][RG + 1];
    __shared__ float sspk[T_STEPS][RG + 1];
    __shared__ int   so[RG];

    const int b = blockIdx.x / RJ;
    const int j = blockIdx.x % RJ;
    const unsigned int n_b = counters[b];
    if (n_b == 0) return;
    const int ngroups = (int)(n_b + RG - 1) / RG;

    const int tid = threadIdx.x;
    const int t   = tid & 63;
    const int oi  = tid >> 6;          // 0..3, owns o-slots 4*oi .. 4*oi+3

    const int ts  = tid >> 2;          // X row 0..63
    const int kq  = (tid & 3) * 16;    // X col quarter
    const int wo  = tid >> 4;          // W row 0..15
    const int wkq = (tid & 15) * 4;    // W col quad

    for (int g = j; g < ngroups; g += RJ) {
        if (tid < RG) {
            const int slot = g * RG + tid;
            so[tid] = (slot < (int)n_b) ? (int)worklist[b * 2048 + slot] : -1;
        }
        __syncthreads();

        float Csum[4] = {0.f, 0.f, 0.f, 0.f};
        float P[4]    = {0.f, 0.f, 0.f, 0.f};

        float4 rx[4];
        float4 rw;
        {
            const float* srcx = &X[(size_t)(ts * BATCH + b) * K_DIM + kq];
#pragma unroll
            for (int q = 0; q < 4; q++) rx[q] = *(const float4*)(srcx + q * 4);
            const int o = so[wo];
            rw = (o >= 0) ? *(const float4*)&W[(size_t)o * K_DIM + wkq]
                          : make_float4(0.f, 0.f, 0.f, 0.f);
        }

        for (int c = 0; c < K_DIM / BKR; c++) {
            if (c > 0 && (c % 5) == 0) {       // k = 320*j panel boundary
#pragma unroll
                for (int q = 0; q < 4; q++) {
                    Csum[q] = __fadd_rn(Csum[q], P[q]);
                    P[q] = 0.f;
                }
            }
            __syncthreads();                   // prev chunk's LDS reads done
#pragma unroll
            for (int q = 0; q < 4; q++) {
                sX[kq + q * 4 + 0][ts] = rx[q].x;
                sX[kq + q * 4 + 1][ts] = rx[q].y;
                sX[kq + q * 4 + 2][ts] = rx[q].z;
                sX[kq + q * 4 + 3][ts] = rx[q].w;
            }
            sW[wo][wkq + 0] = rw.x; sW[wo][wkq + 1] = rw.y;
            sW[wo][wkq + 2] = rw.z; sW[wo][wkq + 3] = rw.w;
            if (c + 1 < K_DIM / BKR) {
                const int k1 = (c + 1) * BKR;
                const float* srcx = &X[(size_t)(ts * BATCH + b) * K_DIM + k1 + kq];
#pragma unroll
                for (int q = 0; q < 4; q++) rx[q] = *(const float4*)(srcx + q * 4);
                const int o = so[wo];
                rw = (o >= 0) ? *(const float4*)&W[(size_t)o * K_DIM + k1 + wkq]
                              : make_float4(0.f, 0.f, 0.f, 0.f);
            }
            __syncthreads();                   // LDS chunk c ready
#pragma unroll 8
            for (int k = 0; k < BKR; k++) {
                const float xv = sX[k][t];
#pragma unroll
                for (int q = 0; q < 4; q++)
                    P[q] = fmaf(xv, sW[oi * 4 + q][k], P[q]);
            }
        }
        __syncthreads();
#pragma unroll
        for (int q = 0; q < 4; q++) {
            Csum[q] = __fadd_rn(Csum[q], P[q]);    // final 128-elem panel
            const int o = so[oi * 4 + q];
            scur[t][oi * 4 + q] = (o >= 0) ? __fadd_rn(Csum[q], bias[o]) : 0.f;
        }
        __syncthreads();
        if (tid < RG && so[tid] >= 0) {
            float mem = 0.0f;
            for (int tt = 0; tt < T_STEPS; tt++) {
                mem = __fadd_rn(__fmul_rn(mem, DECAY_F32), scur[tt][tid]);
                const float d = __fsub_rn(mem, 1.0f);
                const bool spk = d > 0.0f;
                sspk[tt][tid] = spk ? 1.0f : 0.0f;
                if (spk) mem = __fsub_rn(mem, 1.0f);
            }
        }
        __syncthreads();
#pragma unroll
        for (int q = 0; q < 4; q++) {
            const int o = so[oi * 4 + q];
            if (o >= 0)
                out[(size_t)t * NCHAIN + (size_t)b * N_DIM + o] = sspk[t][oi * 4 + q];
        }
        __syncthreads();
    }
}

// ---------------------------------------------------------------------------
// FALLBACK (R8, known-passing, ws-free).
// ---------------------------------------------------------------------------
__global__ __launch_bounds__(256)
void lif_openblas_q320(const float* __restrict__ X, const float* __restrict__ W,
                       const float* __restrict__ bias, float* __restrict__ out) {
    __shared__ float As[16][T_STEPS + 4];
    __shared__ float Ws[16][64 + 4];
    __shared__ float curbuf[T_STEPS][64 + 1];
    const int tid = threadIdx.x;
    const int o0 = blockIdx.x * 64, b0 = blockIdx.y;
    const int tm = (tid & 15) * 4, tn = (tid >> 4) * 4;
    float Csum[4][4], Pacc[4][4];
#pragma unroll
    for (int i = 0; i < 4; i++)
#pragma unroll
        for (int j = 0; j < 4; j++) { Csum[i][j] = 0.f; Pacc[i][j] = 0.f; }
    for (int c = 0; c < K_DIM / 16; c++) {
        if (c > 0 && (c % 20) == 0) {
#pragma unroll
            for (int i = 0; i < 4; i++)
#pragma unroll
                for (int j = 0; j < 4; j++) {
                    Csum[i][j] = __fadd_rn(Csum[i][j], Pacc[i][j]);
                    Pacc[i][j] = 0.f;
                }
        }
        const int k0 = c * 16;
        {
            const int t = tid >> 2, kq = (tid & 3) * 4;
            const float4 av = *(const float4*)&X[(size_t)(t * BATCH + b0) * K_DIM + k0 + kq];
            As[kq + 0][t] = av.x; As[kq + 1][t] = av.y;
            As[kq + 2][t] = av.z; As[kq + 3][t] = av.w;
            const float4 wv = *(const float4*)&W[(size_t)(o0 + t) * K_DIM + k0 + kq];
            Ws[kq + 0][t] = wv.x; Ws[kq + 1][t] = wv.y;
            Ws[kq + 2][t] = wv.z; Ws[kq + 3][t] = wv.w;
        }
        __syncthreads();
#pragma unroll
        for (int k = 0; k < 16; k++) {
            float a[4], w[4];
#pragma unroll
            for (int i = 0; i < 4; i++) a[i] = As[k][tm + i];
#pragma unroll
            for (int j = 0; j < 4; j++) w[j] = Ws[k][tn + j];
#pragma unroll
            for (int i = 0; i < 4; i++)
#pragma unroll
                for (int j = 0; j < 4; j++) Pacc[i][j] = fmaf(a[i], w[j], Pacc[i][j]);
        }
        __syncthreads();
    }
#pragma unroll
    for (int i = 0; i < 4; i++)
#pragma unroll
        for (int j = 0; j < 4; j++)
            curbuf[tm + i][tn + j] =
                __fadd_rn(__fadd_rn(Csum[i][j], Pacc[i][j]), bias[o0 + tn + j]);
    __syncthreads();
    if (tid < 64) {
        float mem = 0.0f;
#pragma unroll
        for (int t = 0; t < T_STEPS; t++) {
            mem = __fadd_rn(__fmul_rn(mem, DECAY_F32), curbuf[t][tid]);
            const float d = __fsub_rn(mem, 1.0f);
            const bool spk = d > 0.0f;
            out[(size_t)t * NCHAIN + (size_t)b0 * N_DIM + o0 + tid] = spk ? 1.0f : 0.0f;
            if (spk) mem = __fsub_rn(mem, 1.0f);
        }
    }
}

extern "C" void kernel_launch(void* const* d_in, const int* in_sizes, int n_in,
                              void* d_out, int out_size, void* d_ws, size_t ws_size,
                              hipStream_t stream) {
    const float* x = nullptr; const float* W = nullptr; const float* bias = nullptr;
    for (int i = 0; i < n_in; i++) {
        if      (in_sizes[i] == M_DIM * K_DIM) x    = (const float*)d_in[i];
        else if (in_sizes[i] == N_DIM * K_DIM) W    = (const float*)d_in[i];
        else if (in_sizes[i] == N_DIM)         bias = (const float*)d_in[i];
    }
    if (!x)    x    = (const float*)d_in[0];
    if (!W)    W    = (const float*)d_in[1];
    if (!bias) bias = (const float*)d_in[2];
    float* out = (float*)d_out;

    // workspace layout: counters + worklist only
    const size_t off_cnt = 0;                                   // 128 u32
    const size_t off_wl  = 512;                                 // 128*2048 u32
    const size_t need    = off_wl + (size_t)128 * 2048 * 4;     // ~1.05 MB

    if (ws_size < need) {
        dim3 grid(N_DIM / 64, BATCH);
        lif_openblas_q320<<<grid, 256, 0, stream>>>(x, W, bias, out);
        return;
    }

    char* ws = (char*)d_ws;
    unsigned int* counters = (unsigned int*)(ws + off_cnt);
    unsigned int* worklist = (unsigned int*)(ws + off_wl);

    hipMemsetAsync(counters, 0, 512, stream);   // graph-capturable

    dim3 ggrid(N_DIM / 128, M_DIM / 256);   // (16, 32) -> 512 tiles
    gemm_lif<<<ggrid, 512, 132096, stream>>>(x, W, bias, out, counters, worklist);
    lif_repair2<<<128 * RJ, 256, 0, stream>>>(x, W, bias, counters, worklist, out);
}